// Round 17
// baseline (246.210 us; speedup 1.0000x reference)
//
#include <hip/hip_runtime.h>
#include <cstdint>
#include <cstddef>
#include <climits>

// ---------------------------------------------------------------------------
// BNN pipeline:
//  L1: conv7x7(sign(x), sign(w1)) -> BN(train) -> leaky(0.5)
//  L2: conv1x1(sign(.), sign(w2)) -> BN(train) -> leaky(0.5)
//  L3: conv5x5 fp32 (64->1)
// Shapes: x (16,1,256,256), out (16,1,256,256)
//
// h2s layout (PADDED in x): int8 [16*64][256][264], col p maps to x = p-2.
//
// conv2: scalar-weight loads; wave-uniform interior fast path.
// conv3: 16x64 tile, 512 thr = 2 teams x 256; teams split each 8-ch LDS
//        chunk (23 KB -> 4 blocks/CU = 32 waves/CU), reg double-buffered
//        staging, dot2, LDS cross-team reduce, direct float4 store.
// stats1: broadcast structure + p-domain interior.
// ---------------------------------------------------------------------------

#define NPIX_PER_CH (16.0 * 256.0 * 256.0)
#define PLANE_BYTES 67584      // 256*264
#define ROW_BYTES   264

typedef _Float16 half2_t __attribute__((ext_vector_type(2)));

#if __has_builtin(__builtin_amdgcn_fdot2)
__device__ __forceinline__ float DOT2(half2_t a, half2_t b, float c) {
    return __builtin_amdgcn_fdot2(a, b, c, false);
}
#else
__device__ __forceinline__ float DOT2(half2_t a, half2_t b, float c) {
    return fmaf((float)a[0], (float)b[0], fmaf((float)a[1], (float)b[1], c));
}
#endif

__device__ __forceinline__ uint32_t pk_f16(float lo, float hi) {
#if __has_builtin(__builtin_amdgcn_cvt_pkrtz)
    auto h = __builtin_amdgcn_cvt_pkrtz(lo, hi);
    return __builtin_bit_cast(uint32_t, h);
#else
    half2_t h; h[0] = (_Float16)lo; h[1] = (_Float16)hi;
    return __builtin_bit_cast(uint32_t, h);
#endif
}
#define H2(u) __builtin_bit_cast(half2_t, (uint32_t)(u))

struct WS {
    int8_t*   h2s;
    uint64_t* xbits;
    uint64_t* wb1;
    uint64_t* w2lo;
    uint64_t* w2hi;
    uint4*    w2pk;               // [64]
    long long* st1;
    long long* st2;
    uint4*    pk1;                // [128] {wb_lo, wb_hi, K, pth}
    unsigned long long* flipm;    // [2]
    float* a2; float* c2;
    uint32_t* wtab;               // [64*32]
};

static inline WS carve(void* d_ws) {
    WS w;
    uint8_t* p = (uint8_t*)d_ws;
    w.h2s   = (int8_t*)p;              p += (size_t)16 * 64 * PLANE_BYTES;
    w.xbits = (uint64_t*)p;            p += (size_t)16 * 256 * 6 * 8;
    w.wb1   = (uint64_t*)p;            p += 128 * 8;
    w.w2lo  = (uint64_t*)p;            p += 64 * 8;
    w.w2hi  = (uint64_t*)p;            p += 64 * 8;
    w.w2pk  = (uint4*)p;               p += 64 * 16;
    w.st1   = (long long*)p;           p += 256 * 8;
    w.st2   = (long long*)p;           p += 128 * 8;
    w.pk1   = (uint4*)p;               p += 128 * 16;
    w.flipm = (unsigned long long*)p;  p += 2 * 8;
    w.a2    = (float*)p;               p += 64 * 4;
    w.c2    = (float*)p;               p += 64 * 4;
    w.wtab  = (uint32_t*)p;            p += 64 * 32 * 4;
    return w;
}

// ---- K0: pack sign bits of x into padded per-row words ---------------------
__global__ __launch_bounds__(256) void k_pack_x(const float* __restrict__ x,
                                                uint64_t* __restrict__ xbits) {
    int rowId = blockIdx.x * 4 + (threadIdx.x >> 6);
    int lane  = threadIdx.x & 63;
    const float* row = x + (size_t)rowId * 256;
    uint64_t b0 = __ballot(row[0 * 64 + lane] < 0.0f);
    uint64_t b1 = __ballot(row[1 * 64 + lane] < 0.0f);
    uint64_t b2 = __ballot(row[2 * 64 + lane] < 0.0f);
    uint64_t b3 = __ballot(row[3 * 64 + lane] < 0.0f);
    if (lane == 0) {
        uint64_t* o = xbits + (size_t)rowId * 6;
        o[0] = b0 << 8;
        o[1] = (b0 >> 56) | (b1 << 8);
        o[2] = (b1 >> 56) | (b2 << 8);
        o[3] = (b2 >> 56) | (b3 << 8);
        o[4] = b3 >> 56;
        o[5] = 0;
    }
}

// ---- K1: pack weight sign bits, zero stat accumulators ---------------------
__global__ void k_pack_w(const float* __restrict__ w1, const float* __restrict__ w2,
                         uint64_t* __restrict__ wb1, uint64_t* __restrict__ w2lo,
                         uint64_t* __restrict__ w2hi, uint4* __restrict__ w2pk,
                         long long* __restrict__ st1, long long* __restrict__ st2) {
    int t = threadIdx.x;
    if (t < 128) {
        uint64_t b = 0;
        for (int k = 0; k < 49; ++k)
            if (w1[t * 49 + k] < 0.0f) b |= (1ull << k);
        wb1[t] = b;
    } else if (t < 192) {
        int o = t - 128;
        uint64_t lo = 0, hi = 0;
        for (int c = 0; c < 64; ++c) if (w2[o * 128 + c]      < 0.0f) lo |= (1ull << c);
        for (int c = 0; c < 64; ++c) if (w2[o * 128 + 64 + c] < 0.0f) hi |= (1ull << c);
        w2lo[o] = lo; w2hi[o] = hi;
        w2pk[o] = make_uint4((uint32_t)lo, (uint32_t)(lo >> 32),
                             (uint32_t)hi, (uint32_t)(hi >> 32));
    }
    st1[t] = 0;
    if (t < 128) st2[t] = 0;
}

// ---- window builder: 49-bit sign window + validity mask --------------------
__device__ inline void build_window(const uint64_t* __restrict__ xb_img, int y, int x,
                                    uint64_t& sbits, uint64_t& vmask) {
    int bitpos = x + 5;
    int w  = bitpos >> 6;
    int sh = bitpos & 63;
    int lo = 3 - x;   if (lo < 0) lo = 0;
    int hi = 258 - x; if (hi > 6) hi = 6;
    uint64_t hm = ((1ull << (hi - lo + 1)) - 1ull) << lo;
    sbits = 0; vmask = 0;
    #pragma unroll
    for (int dy = 0; dy < 7; ++dy) {
        int yy = y - 3 + dy;
        if (yy < 0 || yy > 255) continue;
        const uint64_t* r = xb_img + (size_t)yy * 6;
        uint64_t wA = r[w], wB = r[w + 1];
        uint64_t bits = wA >> sh;
        if (sh) bits |= wB << (64 - sh);
        bits &= 0x7Full;
        sbits |= bits << (7 * dy);
        vmask |= hm   << (7 * dy);
    }
}

// ---- K2: layer-1 BN statistics; p-domain interior + broadcast reads ---------
__global__ __launch_bounds__(256) void k_stats1(const uint64_t* __restrict__ xbits,
                                                const uint64_t* __restrict__ wb1g,
                                                long long* __restrict__ st1) {
    __shared__ uint64_t sb[256];
    __shared__ uint64_t vm[256];
    __shared__ int rs[128];
    __shared__ int rq[128];
    int t = threadIdx.x;
    int c = t & 127, half = t >> 7;
    uint64_t wb = wb1g[c];
    int sumE = 0, sqE = 0;
    int sumP = 0, sumPP = 0, nF = 0;
    for (int row = blockIdx.x; row < 4096; row += gridDim.x) {
        int n = row >> 8, y = row & 255;
        const uint64_t* xb_img = xbits + (size_t)n * 256 * 6;
        uint64_t s, v;
        build_window(xb_img, y, t, s, v);
        sb[t] = s; vm[t] = v;
        __syncthreads();
        int base = half << 7;
        auto edge = [&](int p) {
            uint64_t vv = vm[base + p];
            uint64_t d = (sb[base + p] ^ wb) & vv;
            int h = __popcll(vv) - 2 * __popcll(d);
            sumE += h; sqE += h * h;
        };
        if (y >= 3 && y <= 252) {
            int lo = (half == 0) ? 3 : 0;
            int hi = (half == 0) ? 128 : 125;
            for (int p = 0; p < lo; ++p) edge(p);
            #pragma unroll 4
            for (int p = lo; p < hi; ++p) {
                int pc = __popcll(sb[base + p] ^ wb);
                sumP += pc; sumPP += pc * pc;
            }
            for (int p = hi; p < 128; ++p) edge(p);
            nF += hi - lo;
        } else {
            #pragma unroll 4
            for (int p = 0; p < 128; ++p) edge(p);
        }
        __syncthreads();
    }
    int sum   = sumE + 49 * nF - 2 * sumP;
    int sumsq = sqE + 2401 * nF - 196 * sumP + 4 * sumPP;
    if (half == 1) { rs[c] = sum; rq[c] = sumsq; }
    __syncthreads();
    if (half == 0) {
        long long S = (long long)sum + rs[c];
        long long Q = (long long)sumsq + rq[c];
        atomicAdd((unsigned long long*)&st1[c],       (unsigned long long)S);
        atomicAdd((unsigned long long*)&st1[128 + c], (unsigned long long)Q);
    }
}

// ---- K3: BN1 -> {wb, K, pth} pack -------------------------------------------
__global__ void k_fin1(const long long* __restrict__ st1,
                       const float* __restrict__ g1, const float* __restrict__ b1,
                       const uint64_t* __restrict__ wb1,
                       uint4* __restrict__ pk1, unsigned long long* __restrict__ flipm) {
    int c = threadIdx.x;            // 128 threads
    double mean = (double)st1[c] / NPIX_PER_CH;
    double var  = (double)st1[128 + c] / NPIX_PER_CH - mean * mean;
    double a = (double)g1[c] / sqrt(var + 1e-5);
    double cst = (double)b1[c] - mean * a;
    int K; int flip = 0;
    if (a > 0.0) {
        double v = -cst / a;
        v = fmin(fmax(v, -100.0), 100.0);
        K = (int)ceil(v);
    } else if (a < 0.0) {
        double v = -cst / a;
        v = fmin(fmax(v, -100.0), 100.0);
        K = (int)floor(v) + 1; flip = 1;
    } else {
        K = INT_MIN; flip = (cst < 0.0) ? 1 : 0;
    }
    long long pt = ((49LL - (long long)K) >> 1) + 1;
    if (pt < 0) pt = 0;
    if (pt > 50) pt = 50;
    uint64_t wb = wb1[c];
    pk1[c] = make_uint4((uint32_t)wb, (uint32_t)(wb >> 32), (uint32_t)K, (uint32_t)pt);
    unsigned long long m = __ballot(flip != 0);
    if ((c & 63) == 0) flipm[c >> 6] = m;
}

// ---- K4: fused conv1-sign -> conv2 -> h2/2; wave-uniform fast path ----------
__global__ __launch_bounds__(256) void k_conv2(const uint64_t* __restrict__ xbits,
                                               const uint4* __restrict__ pk1,
                                               const unsigned long long* __restrict__ flipm,
                                               const uint4* __restrict__ w2pk,
                                               int8_t* __restrict__ h2s) {
    int t = threadIdx.x;
    int n = blockIdx.x >> 8, y = blockIdx.x & 255, x = t;
    const uint64_t* xb_img = xbits + (size_t)n * 256 * 6;
    uint64_t sbits, vmask;
    build_window(xb_img, y, x, sbits, vmask);
    int nv = __popcll(vmask);

    uint32_t bw0 = 0, bw1 = 0, bw2 = 0, bw3 = 0;
    int wvid = __builtin_amdgcn_readfirstlane(t >> 6);
    bool fastw = (y >= 3 && y <= 252) && (wvid == 1 || wvid == 2);
    if (fastw) {
        #pragma unroll
        for (int cc = 0; cc < 128; ++cc) {
            uint4 pk = pk1[cc];
            uint64_t wb = ((uint64_t)pk.y << 32) | pk.x;
            int pc = __popcll(sbits ^ wb);
            uint32_t b = (uint32_t)(pc >= (int)pk.w) << (cc & 31);
            if (cc < 32)       bw0 |= b;
            else if (cc < 64)  bw1 |= b;
            else if (cc < 96)  bw2 |= b;
            else               bw3 |= b;
        }
    } else {
        #pragma unroll
        for (int cc = 0; cc < 128; ++cc) {
            uint4 pk = pk1[cc];
            uint64_t wb = ((uint64_t)pk.y << 32) | pk.x;
            int h = nv - 2 * __popcll((sbits ^ wb) & vmask);
            uint32_t b = (uint32_t)(h < (int)pk.z) << (cc & 31);
            if (cc < 32)       bw0 |= b;
            else if (cc < 64)  bw1 |= b;
            else if (cc < 96)  bw2 |= b;
            else               bw3 |= b;
        }
    }
    unsigned long long f0 = flipm[0], f1 = flipm[1];
    bw0 ^= (uint32_t)f0; bw1 ^= (uint32_t)(f0 >> 32);
    bw2 ^= (uint32_t)f1; bw3 ^= (uint32_t)(f1 >> 32);

    size_t base = (size_t)(n * 64) * PLANE_BYTES + (size_t)y * ROW_BYTES;
    #pragma unroll
    for (int o = 0; o < 64; ++o) {
        uint4 w = w2pk[o];
        int m = __popc(bw0 ^ w.x) + __popc(bw1 ^ w.y)
              + __popc(bw2 ^ w.z) + __popc(bw3 ^ w.w);
        h2s[base + (size_t)o * PLANE_BYTES + 2 + x] = (int8_t)(64 - m);
    }
    if (x == 0) {
        #pragma unroll 8
        for (int o = 0; o < 64; ++o)
            *(short*)(h2s + base + (size_t)o * PLANE_BYTES) = 0;
    }
    if (x == 255) {
        #pragma unroll 8
        for (int o = 0; o < 64; ++o) {
            int8_t* r = h2s + base + (size_t)o * PLANE_BYTES;
            *(short*)(r + 258) = 0;
            *(int*)(r + 260) = 0;
        }
    }
}

// ---- K5: layer-2 BN statistics (on stored v = h2/2, padded layout) ----------
__global__ __launch_bounds__(256) void k_stats2(const int8_t* __restrict__ h2s,
                                                long long* __restrict__ st2) {
    int plane = blockIdx.x;       // n*64 + o
    int o = plane & 63;
    int t = threadIdx.x;
    const int4* p = (const int4*)(h2s + (size_t)plane * PLANE_BYTES);
    int sum = 0, sumsq = 0;
    for (int si = t; si < 4224; si += 256) {
        int4 v4 = p[si];
        int wv[4] = {v4.x, v4.y, v4.z, v4.w};
        #pragma unroll
        for (int j = 0; j < 4; ++j) {
            #pragma unroll
            for (int k = 0; k < 4; ++k) {
                int b = (int)(int8_t)((unsigned)wv[j] >> (8 * k));
                sum += b;
                sumsq += b * b;
            }
        }
    }
    for (int off = 32; off; off >>= 1) {
        sum   += __shfl_down(sum, off);
        sumsq += __shfl_down(sumsq, off);
    }
    __shared__ int ws1[4], ws2[4];
    int wid = t >> 6;
    if ((t & 63) == 0) { ws1[wid] = sum; ws2[wid] = sumsq; }
    __syncthreads();
    if (t == 0) {
        long long S = 0, Q = 0;
        for (int i = 0; i < 4; ++i) { S += ws1[i]; Q += ws2[i]; }
        atomicAdd((unsigned long long*)&st2[o],      (unsigned long long)S);
        atomicAdd((unsigned long long*)&st2[64 + o], (unsigned long long)Q);
    }
}

// ---- K6: BN2 coefficients + packed-f16 conv3 weight table -------------------
__global__ void k_fin2(const long long* __restrict__ st2,
                       const float* __restrict__ g2, const float* __restrict__ b2,
                       const float* __restrict__ w3,
                       float* __restrict__ a2, float* __restrict__ c2,
                       uint32_t* __restrict__ wtab) {
    int o = threadIdx.x;            // 64 threads
    double mean = 2.0 * (double)st2[o] / NPIX_PER_CH;
    double msq  = 4.0 * (double)st2[64 + o] / NPIX_PER_CH;
    double var  = msq - mean * mean;
    double inv  = (double)g2[o] / sqrt(var + 1e-5);
    a2[o] = (float)(2.0 * inv);
    c2[o] = (float)((double)b2[o] - mean * inv);

    uint32_t* wp = wtab + o * 32;
    #pragma unroll
    for (int dy = 0; dy < 5; ++dy) {
        float w0 = w3[o * 25 + dy * 5 + 0];
        float w1 = w3[o * 25 + dy * 5 + 1];
        float w2v = w3[o * 25 + dy * 5 + 2];
        float w3v = w3[o * 25 + dy * 5 + 3];
        float w4 = w3[o * 25 + dy * 5 + 4];
        half2_t h;
        h[0] = (_Float16)w0;  h[1] = (_Float16)w1;  wp[dy*6+0] = __builtin_bit_cast(uint32_t, h);
        h[0] = (_Float16)w2v; h[1] = (_Float16)w3v; wp[dy*6+1] = __builtin_bit_cast(uint32_t, h);
        h[0] = (_Float16)w4;  h[1] = (_Float16)0.f; wp[dy*6+2] = __builtin_bit_cast(uint32_t, h);
        h[0] = (_Float16)0.f; h[1] = (_Float16)w0;  wp[dy*6+3] = __builtin_bit_cast(uint32_t, h);
        h[0] = (_Float16)w1;  h[1] = (_Float16)w2v; wp[dy*6+4] = __builtin_bit_cast(uint32_t, h);
        h[0] = (_Float16)w3v; h[1] = (_Float16)w4;  wp[dy*6+5] = __builtin_bit_cast(uint32_t, h);
    }
    wp[30] = 0; wp[31] = 0;
}

// ---- K7: conv3 5x5 — 16x64 tile, 2 channel-teams, LDS reduce, direct store --
// grid: 16 n * 16 yt * 4 xt = 1024 blocks (4/CU, 32 waves/CU).
// LDS: 8ch x 20rows x 72cols f16 = 23040 B. Team thread: 1y x 4x outputs,
// 4 of the 8 chunk channels; cross-team float4 reduce at the end.
__global__ __launch_bounds__(512, 8) void k_conv3(const int8_t* __restrict__ h2s,
                                                  const float* __restrict__ a2g,
                                                  const float* __restrict__ c2g,
                                                  const uint32_t* __restrict__ wtab,
                                                  float* __restrict__ out) {
    __shared__ uint16_t lds[8 * 20 * 72];       // ch stride 1440, row 72
    __shared__ float sA2[64], sC2[64];
    int t = threadIdx.x;
    int bid = blockIdx.x;                // 0..1023
    int n  = bid >> 6;
    int yt = (bid >> 2) & 15;
    int xt = bid & 3;
    int ty0 = yt * 16, tx0 = xt * 64;
    if (t < 64) { sA2[t] = a2g[t]; sC2[t] = c2g[t]; }

    int team = t >> 8;                   // 0..1
    int tyx  = t & 255;
    int ty = tyx >> 4, tx = tyx & 15;    // out row ty0+ty, cols tx0+4tx..+3
    int pbase = n * 64;

    // staging metadata: 8ch x 20rows x 17quads = 2720 items, 6 slots/thread
    int s_cl[6], s_lds[6];
    const int8_t* s_ptr[6];
    bool s_has[6], s_ok[6];
    #pragma unroll
    for (int it = 0; it < 6; ++it) {
        int si = t + 512 * it;
        int cl  = si / 340;              // 340 = 20*17, cl 0..7
        int rem = si - cl * 340;
        int row = rem / 17;
        int q   = rem - row * 17;
        int gy  = ty0 - 2 + row;
        bool has = (si < 2720);
        bool ok  = has && ((unsigned)gy < 256u);
        int clc = has ? cl : 0;
        s_cl[it]  = clc;
        s_lds[it] = clc * 1440 + row * 72 + q * 4;
        s_ptr[it] = h2s + (size_t)(pbase + clc) * PLANE_BYTES
                        + (size_t)(ok ? gy : 0) * ROW_BYTES + tx0 + q * 4;
        s_has[it] = has; s_ok[it] = ok;
    }
    int vv[6];
    #pragma unroll
    for (int it = 0; it < 6; ++it)
        vv[it] = s_ok[it] ? *(const int*)s_ptr[it] : 0;

    float acc[4] = {0.f, 0.f, 0.f, 0.f};
    int clbase = team * 4;

    for (int kk = 0; kk < 8; ++kk) {     // 8 chunks x 8 channels = 64 ch
        __syncthreads();                 // first iter also guards sA2/sC2
        #pragma unroll
        for (int it = 0; it < 6; ++it) {
            if (s_has[it]) {
                int lc = 8 * kk + s_cl[it];
                float a = sA2[lc], c = sC2[lc];
                int v = vv[it];
                float z0 = fmaf(a, (float)(int)(int8_t)(v),        c);
                float z1 = fmaf(a, (float)(int)(int8_t)(v >> 8),   c);
                float z2 = fmaf(a, (float)(int)(int8_t)(v >> 16),  c);
                float z3 = fmaf(a, (float)(int)(int8_t)(v >> 24),  c);
                z0 = fmaxf(z0, 0.5f * z0);
                z1 = fmaxf(z1, 0.5f * z1);
                z2 = fmaxf(z2, 0.5f * z2);
                z3 = fmaxf(z3, 0.5f * z3);
                uint2 wv2 = {pk_f16(z0, z1), pk_f16(z2, z3)};
                *(uint2*)(lds + s_lds[it]) = wv2;
            }
        }
        __syncthreads();
        if (kk < 7) {                    // prefetch next chunk (overlaps compute)
            #pragma unroll
            for (int it = 0; it < 6; ++it) {
                s_ptr[it] += 8 * PLANE_BYTES;
                vv[it] = s_ok[it] ? *(const int*)s_ptr[it] : 0;
            }
        }

        #pragma unroll
        for (int cl = 0; cl < 4; ++cl) {           // team's 4 channels
            int lc = clbase + cl;
            const uint32_t* wp = wtab + (size_t)(8 * kk + lc) * 32;   // uniform
            const uint16_t* base = lds + lc * 1440 + ty * 72 + 4 * tx;
            uint2 A[5], B[5];
            #pragma unroll
            for (int rr = 0; rr < 5; ++rr) {      // batched: 10 ds_read_b64
                A[rr] = *(const uint2*)(base + rr * 72);
                B[rr] = *(const uint2*)(base + rr * 72 + 4);
            }
            #pragma unroll
            for (int rr = 0; rr < 5; ++rr) {      // dyp == rr (single out row)
                half2_t W0 = H2(A[rr].x), W1 = H2(A[rr].y);
                half2_t W2 = H2(B[rr].x), W3 = H2(B[rr].y);
                const uint32_t* wd = wp + rr * 6;
                acc[0] = DOT2(W0, H2(wd[0]), DOT2(W1, H2(wd[1]), DOT2(W2, H2(wd[2]), acc[0])));
                acc[1] = DOT2(W0, H2(wd[3]), DOT2(W1, H2(wd[4]), DOT2(W2, H2(wd[5]), acc[1])));
                acc[2] = DOT2(W1, H2(wd[0]), DOT2(W2, H2(wd[1]), DOT2(W3, H2(wd[2]), acc[2])));
                acc[3] = DOT2(W1, H2(wd[3]), DOT2(W2, H2(wd[4]), DOT2(W3, H2(wd[5]), acc[3])));
            }
        }
    }

    // cross-team reduction (reuse lds; all compute reads are done)
    __syncthreads();
    float4* red = (float4*)lds;
    if (team == 1) {
        float4 r = {acc[0], acc[1], acc[2], acc[3]};
        red[tyx] = r;
    }
    __syncthreads();
    if (team == 0) {
        float4 o2 = red[tyx];
        int oy = ty0 + ty;
        int ox = tx0 + 4 * tx;
        float4 r = {acc[0] + o2.x, acc[1] + o2.y, acc[2] + o2.z, acc[3] + o2.w};
        *(float4*)(out + (size_t)n * 65536 + (size_t)oy * 256 + ox) = r;
    }
}

// ---------------------------------------------------------------------------
extern "C" void kernel_launch(void* const* d_in, const int* in_sizes, int n_in,
                              void* d_out, int out_size, void* d_ws, size_t ws_size,
                              hipStream_t stream) {
    const float* x  = (const float*)d_in[0];
    const float* w1 = (const float*)d_in[1];
    const float* g1 = (const float*)d_in[2];
    const float* b1 = (const float*)d_in[3];
    const float* w2 = (const float*)d_in[4];
    const float* g2 = (const float*)d_in[5];
    const float* b2 = (const float*)d_in[6];
    const float* w3 = (const float*)d_in[7];
    float* out = (float*)d_out;

    WS ws = carve(d_ws);

    k_pack_x<<<1024, 256, 0, stream>>>(x, ws.xbits);
    k_pack_w<<<1, 256, 0, stream>>>(w1, w2, ws.wb1, ws.w2lo, ws.w2hi, ws.w2pk,
                                    ws.st1, ws.st2);
    k_stats1<<<2048, 256, 0, stream>>>(ws.xbits, ws.wb1, ws.st1);
    k_fin1<<<1, 128, 0, stream>>>(ws.st1, g1, b1, ws.wb1, ws.pk1, ws.flipm);
    k_conv2<<<4096, 256, 0, stream>>>(ws.xbits, ws.pk1, ws.flipm, ws.w2pk, ws.h2s);
    k_stats2<<<1024, 256, 0, stream>>>(ws.h2s, ws.st2);
    k_fin2<<<1, 64, 0, stream>>>(ws.st2, g2, b2, w3, ws.a2, ws.c2, ws.wtab);
    k_conv3<<<1024, 512, 0, stream>>>(ws.h2s, ws.a2, ws.c2, ws.wtab, out);
}

// Round 18
// 209.536 us; speedup vs baseline: 1.1750x; 1.1750x over previous
//
#include <hip/hip_runtime.h>
#include <cstdint>
#include <cstddef>
#include <climits>

// ---------------------------------------------------------------------------
// BNN pipeline:
//  L1: conv7x7(sign(x), sign(w1)) -> BN(train) -> leaky(0.5)
//  L2: conv1x1(sign(.), sign(w2)) -> BN(train) -> leaky(0.5)
//  L3: conv5x5 fp32 (64->1)
// Shapes: x (16,1,256,256), out (16,1,256,256)
//
// h2s layout (PADDED in x): int8 [16*64][256][264], col p maps to x = p-2.
//
// conv2: scalar-weight loads; wave-uniform interior fast path.
// conv3: R13 structure (A/B-proven best over 5 variants): 512-thread blocks,
//        32x64 tile, 1y x 4x px/thread, 8-ch f16 LDS chunks (41.5 KB,
//        2 blocks/CU, 16 waves/CU), reg double-buffered staging, dot2,
//        direct float4 store. Variants that regressed: 2y/4x low-occ (83us),
//        cross-block channel split + atomics (95us), in-block team split
//        (106us). 68us is the robust optimum of this structure family.
// stats1: broadcast structure + p-domain interior.
// ---------------------------------------------------------------------------

#define NPIX_PER_CH (16.0 * 256.0 * 256.0)
#define PLANE_BYTES 67584      // 256*264
#define ROW_BYTES   264

typedef _Float16 half2_t __attribute__((ext_vector_type(2)));

#if __has_builtin(__builtin_amdgcn_fdot2)
__device__ __forceinline__ float DOT2(half2_t a, half2_t b, float c) {
    return __builtin_amdgcn_fdot2(a, b, c, false);
}
#else
__device__ __forceinline__ float DOT2(half2_t a, half2_t b, float c) {
    return fmaf((float)a[0], (float)b[0], fmaf((float)a[1], (float)b[1], c));
}
#endif

__device__ __forceinline__ uint32_t pk_f16(float lo, float hi) {
#if __has_builtin(__builtin_amdgcn_cvt_pkrtz)
    auto h = __builtin_amdgcn_cvt_pkrtz(lo, hi);
    return __builtin_bit_cast(uint32_t, h);
#else
    half2_t h; h[0] = (_Float16)lo; h[1] = (_Float16)hi;
    return __builtin_bit_cast(uint32_t, h);
#endif
}
#define H2(u) __builtin_bit_cast(half2_t, (uint32_t)(u))

struct WS {
    int8_t*   h2s;
    uint64_t* xbits;
    uint64_t* wb1;
    uint64_t* w2lo;
    uint64_t* w2hi;
    uint4*    w2pk;               // [64]
    long long* st1;
    long long* st2;
    uint4*    pk1;                // [128] {wb_lo, wb_hi, K, pth}
    unsigned long long* flipm;    // [2]
    float* a2; float* c2;
    uint32_t* wtab;               // [64*32]
};

static inline WS carve(void* d_ws) {
    WS w;
    uint8_t* p = (uint8_t*)d_ws;
    w.h2s   = (int8_t*)p;              p += (size_t)16 * 64 * PLANE_BYTES;
    w.xbits = (uint64_t*)p;            p += (size_t)16 * 256 * 6 * 8;
    w.wb1   = (uint64_t*)p;            p += 128 * 8;
    w.w2lo  = (uint64_t*)p;            p += 64 * 8;
    w.w2hi  = (uint64_t*)p;            p += 64 * 8;
    w.w2pk  = (uint4*)p;               p += 64 * 16;
    w.st1   = (long long*)p;           p += 256 * 8;
    w.st2   = (long long*)p;           p += 128 * 8;
    w.pk1   = (uint4*)p;               p += 128 * 16;
    w.flipm = (unsigned long long*)p;  p += 2 * 8;
    w.a2    = (float*)p;               p += 64 * 4;
    w.c2    = (float*)p;               p += 64 * 4;
    w.wtab  = (uint32_t*)p;            p += 64 * 32 * 4;
    return w;
}

// ---- K0: pack sign bits of x into padded per-row words ---------------------
__global__ __launch_bounds__(256) void k_pack_x(const float* __restrict__ x,
                                                uint64_t* __restrict__ xbits) {
    int rowId = blockIdx.x * 4 + (threadIdx.x >> 6);
    int lane  = threadIdx.x & 63;
    const float* row = x + (size_t)rowId * 256;
    uint64_t b0 = __ballot(row[0 * 64 + lane] < 0.0f);
    uint64_t b1 = __ballot(row[1 * 64 + lane] < 0.0f);
    uint64_t b2 = __ballot(row[2 * 64 + lane] < 0.0f);
    uint64_t b3 = __ballot(row[3 * 64 + lane] < 0.0f);
    if (lane == 0) {
        uint64_t* o = xbits + (size_t)rowId * 6;
        o[0] = b0 << 8;
        o[1] = (b0 >> 56) | (b1 << 8);
        o[2] = (b1 >> 56) | (b2 << 8);
        o[3] = (b2 >> 56) | (b3 << 8);
        o[4] = b3 >> 56;
        o[5] = 0;
    }
}

// ---- K1: pack weight sign bits, zero stat accumulators ---------------------
__global__ void k_pack_w(const float* __restrict__ w1, const float* __restrict__ w2,
                         uint64_t* __restrict__ wb1, uint64_t* __restrict__ w2lo,
                         uint64_t* __restrict__ w2hi, uint4* __restrict__ w2pk,
                         long long* __restrict__ st1, long long* __restrict__ st2) {
    int t = threadIdx.x;
    if (t < 128) {
        uint64_t b = 0;
        for (int k = 0; k < 49; ++k)
            if (w1[t * 49 + k] < 0.0f) b |= (1ull << k);
        wb1[t] = b;
    } else if (t < 192) {
        int o = t - 128;
        uint64_t lo = 0, hi = 0;
        for (int c = 0; c < 64; ++c) if (w2[o * 128 + c]      < 0.0f) lo |= (1ull << c);
        for (int c = 0; c < 64; ++c) if (w2[o * 128 + 64 + c] < 0.0f) hi |= (1ull << c);
        w2lo[o] = lo; w2hi[o] = hi;
        w2pk[o] = make_uint4((uint32_t)lo, (uint32_t)(lo >> 32),
                             (uint32_t)hi, (uint32_t)(hi >> 32));
    }
    st1[t] = 0;
    if (t < 128) st2[t] = 0;
}

// ---- window builder: 49-bit sign window + validity mask --------------------
__device__ inline void build_window(const uint64_t* __restrict__ xb_img, int y, int x,
                                    uint64_t& sbits, uint64_t& vmask) {
    int bitpos = x + 5;
    int w  = bitpos >> 6;
    int sh = bitpos & 63;
    int lo = 3 - x;   if (lo < 0) lo = 0;
    int hi = 258 - x; if (hi > 6) hi = 6;
    uint64_t hm = ((1ull << (hi - lo + 1)) - 1ull) << lo;
    sbits = 0; vmask = 0;
    #pragma unroll
    for (int dy = 0; dy < 7; ++dy) {
        int yy = y - 3 + dy;
        if (yy < 0 || yy > 255) continue;
        const uint64_t* r = xb_img + (size_t)yy * 6;
        uint64_t wA = r[w], wB = r[w + 1];
        uint64_t bits = wA >> sh;
        if (sh) bits |= wB << (64 - sh);
        bits &= 0x7Full;
        sbits |= bits << (7 * dy);
        vmask |= hm   << (7 * dy);
    }
}

// ---- K2: layer-1 BN statistics; p-domain interior + broadcast reads ---------
__global__ __launch_bounds__(256) void k_stats1(const uint64_t* __restrict__ xbits,
                                                const uint64_t* __restrict__ wb1g,
                                                long long* __restrict__ st1) {
    __shared__ uint64_t sb[256];
    __shared__ uint64_t vm[256];
    __shared__ int rs[128];
    __shared__ int rq[128];
    int t = threadIdx.x;
    int c = t & 127, half = t >> 7;
    uint64_t wb = wb1g[c];
    int sumE = 0, sqE = 0;
    int sumP = 0, sumPP = 0, nF = 0;
    for (int row = blockIdx.x; row < 4096; row += gridDim.x) {
        int n = row >> 8, y = row & 255;
        const uint64_t* xb_img = xbits + (size_t)n * 256 * 6;
        uint64_t s, v;
        build_window(xb_img, y, t, s, v);
        sb[t] = s; vm[t] = v;
        __syncthreads();
        int base = half << 7;
        auto edge = [&](int p) {
            uint64_t vv = vm[base + p];
            uint64_t d = (sb[base + p] ^ wb) & vv;
            int h = __popcll(vv) - 2 * __popcll(d);
            sumE += h; sqE += h * h;
        };
        if (y >= 3 && y <= 252) {
            int lo = (half == 0) ? 3 : 0;
            int hi = (half == 0) ? 128 : 125;
            for (int p = 0; p < lo; ++p) edge(p);
            #pragma unroll 4
            for (int p = lo; p < hi; ++p) {
                int pc = __popcll(sb[base + p] ^ wb);
                sumP += pc; sumPP += pc * pc;
            }
            for (int p = hi; p < 128; ++p) edge(p);
            nF += hi - lo;
        } else {
            #pragma unroll 4
            for (int p = 0; p < 128; ++p) edge(p);
        }
        __syncthreads();
    }
    int sum   = sumE + 49 * nF - 2 * sumP;
    int sumsq = sqE + 2401 * nF - 196 * sumP + 4 * sumPP;
    if (half == 1) { rs[c] = sum; rq[c] = sumsq; }
    __syncthreads();
    if (half == 0) {
        long long S = (long long)sum + rs[c];
        long long Q = (long long)sumsq + rq[c];
        atomicAdd((unsigned long long*)&st1[c],       (unsigned long long)S);
        atomicAdd((unsigned long long*)&st1[128 + c], (unsigned long long)Q);
    }
}

// ---- K3: BN1 -> {wb, K, pth} pack -------------------------------------------
__global__ void k_fin1(const long long* __restrict__ st1,
                       const float* __restrict__ g1, const float* __restrict__ b1,
                       const uint64_t* __restrict__ wb1,
                       uint4* __restrict__ pk1, unsigned long long* __restrict__ flipm) {
    int c = threadIdx.x;            // 128 threads
    double mean = (double)st1[c] / NPIX_PER_CH;
    double var  = (double)st1[128 + c] / NPIX_PER_CH - mean * mean;
    double a = (double)g1[c] / sqrt(var + 1e-5);
    double cst = (double)b1[c] - mean * a;
    int K; int flip = 0;
    if (a > 0.0) {
        double v = -cst / a;
        v = fmin(fmax(v, -100.0), 100.0);
        K = (int)ceil(v);
    } else if (a < 0.0) {
        double v = -cst / a;
        v = fmin(fmax(v, -100.0), 100.0);
        K = (int)floor(v) + 1; flip = 1;
    } else {
        K = INT_MIN; flip = (cst < 0.0) ? 1 : 0;
    }
    long long pt = ((49LL - (long long)K) >> 1) + 1;
    if (pt < 0) pt = 0;
    if (pt > 50) pt = 50;
    uint64_t wb = wb1[c];
    pk1[c] = make_uint4((uint32_t)wb, (uint32_t)(wb >> 32), (uint32_t)K, (uint32_t)pt);
    unsigned long long m = __ballot(flip != 0);
    if ((c & 63) == 0) flipm[c >> 6] = m;
}

// ---- K4: fused conv1-sign -> conv2 -> h2/2; wave-uniform fast path ----------
__global__ __launch_bounds__(256) void k_conv2(const uint64_t* __restrict__ xbits,
                                               const uint4* __restrict__ pk1,
                                               const unsigned long long* __restrict__ flipm,
                                               const uint4* __restrict__ w2pk,
                                               int8_t* __restrict__ h2s) {
    int t = threadIdx.x;
    int n = blockIdx.x >> 8, y = blockIdx.x & 255, x = t;
    const uint64_t* xb_img = xbits + (size_t)n * 256 * 6;
    uint64_t sbits, vmask;
    build_window(xb_img, y, x, sbits, vmask);
    int nv = __popcll(vmask);

    uint32_t bw0 = 0, bw1 = 0, bw2 = 0, bw3 = 0;
    int wvid = __builtin_amdgcn_readfirstlane(t >> 6);
    bool fastw = (y >= 3 && y <= 252) && (wvid == 1 || wvid == 2);
    if (fastw) {
        #pragma unroll
        for (int cc = 0; cc < 128; ++cc) {
            uint4 pk = pk1[cc];
            uint64_t wb = ((uint64_t)pk.y << 32) | pk.x;
            int pc = __popcll(sbits ^ wb);
            uint32_t b = (uint32_t)(pc >= (int)pk.w) << (cc & 31);
            if (cc < 32)       bw0 |= b;
            else if (cc < 64)  bw1 |= b;
            else if (cc < 96)  bw2 |= b;
            else               bw3 |= b;
        }
    } else {
        #pragma unroll
        for (int cc = 0; cc < 128; ++cc) {
            uint4 pk = pk1[cc];
            uint64_t wb = ((uint64_t)pk.y << 32) | pk.x;
            int h = nv - 2 * __popcll((sbits ^ wb) & vmask);
            uint32_t b = (uint32_t)(h < (int)pk.z) << (cc & 31);
            if (cc < 32)       bw0 |= b;
            else if (cc < 64)  bw1 |= b;
            else if (cc < 96)  bw2 |= b;
            else               bw3 |= b;
        }
    }
    unsigned long long f0 = flipm[0], f1 = flipm[1];
    bw0 ^= (uint32_t)f0; bw1 ^= (uint32_t)(f0 >> 32);
    bw2 ^= (uint32_t)f1; bw3 ^= (uint32_t)(f1 >> 32);

    size_t base = (size_t)(n * 64) * PLANE_BYTES + (size_t)y * ROW_BYTES;
    #pragma unroll
    for (int o = 0; o < 64; ++o) {
        uint4 w = w2pk[o];
        int m = __popc(bw0 ^ w.x) + __popc(bw1 ^ w.y)
              + __popc(bw2 ^ w.z) + __popc(bw3 ^ w.w);
        h2s[base + (size_t)o * PLANE_BYTES + 2 + x] = (int8_t)(64 - m);
    }
    if (x == 0) {
        #pragma unroll 8
        for (int o = 0; o < 64; ++o)
            *(short*)(h2s + base + (size_t)o * PLANE_BYTES) = 0;
    }
    if (x == 255) {
        #pragma unroll 8
        for (int o = 0; o < 64; ++o) {
            int8_t* r = h2s + base + (size_t)o * PLANE_BYTES;
            *(short*)(r + 258) = 0;
            *(int*)(r + 260) = 0;
        }
    }
}

// ---- K5: layer-2 BN statistics (on stored v = h2/2, padded layout) ----------
__global__ __launch_bounds__(256) void k_stats2(const int8_t* __restrict__ h2s,
                                                long long* __restrict__ st2) {
    int plane = blockIdx.x;       // n*64 + o
    int o = plane & 63;
    int t = threadIdx.x;
    const int4* p = (const int4*)(h2s + (size_t)plane * PLANE_BYTES);
    int sum = 0, sumsq = 0;
    for (int si = t; si < 4224; si += 256) {
        int4 v4 = p[si];
        int wv[4] = {v4.x, v4.y, v4.z, v4.w};
        #pragma unroll
        for (int j = 0; j < 4; ++j) {
            #pragma unroll
            for (int k = 0; k < 4; ++k) {
                int b = (int)(int8_t)((unsigned)wv[j] >> (8 * k));
                sum += b;
                sumsq += b * b;
            }
        }
    }
    for (int off = 32; off; off >>= 1) {
        sum   += __shfl_down(sum, off);
        sumsq += __shfl_down(sumsq, off);
    }
    __shared__ int ws1[4], ws2[4];
    int wid = t >> 6;
    if ((t & 63) == 0) { ws1[wid] = sum; ws2[wid] = sumsq; }
    __syncthreads();
    if (t == 0) {
        long long S = 0, Q = 0;
        for (int i = 0; i < 4; ++i) { S += ws1[i]; Q += ws2[i]; }
        atomicAdd((unsigned long long*)&st2[o],      (unsigned long long)S);
        atomicAdd((unsigned long long*)&st2[64 + o], (unsigned long long)Q);
    }
}

// ---- K6: BN2 coefficients + packed-f16 conv3 weight table -------------------
__global__ void k_fin2(const long long* __restrict__ st2,
                       const float* __restrict__ g2, const float* __restrict__ b2,
                       const float* __restrict__ w3,
                       float* __restrict__ a2, float* __restrict__ c2,
                       uint32_t* __restrict__ wtab) {
    int o = threadIdx.x;            // 64 threads
    double mean = 2.0 * (double)st2[o] / NPIX_PER_CH;
    double msq  = 4.0 * (double)st2[64 + o] / NPIX_PER_CH;
    double var  = msq - mean * mean;
    double inv  = (double)g2[o] / sqrt(var + 1e-5);
    a2[o] = (float)(2.0 * inv);
    c2[o] = (float)((double)b2[o] - mean * inv);

    uint32_t* wp = wtab + o * 32;
    #pragma unroll
    for (int dy = 0; dy < 5; ++dy) {
        float w0 = w3[o * 25 + dy * 5 + 0];
        float w1 = w3[o * 25 + dy * 5 + 1];
        float w2v = w3[o * 25 + dy * 5 + 2];
        float w3v = w3[o * 25 + dy * 5 + 3];
        float w4 = w3[o * 25 + dy * 5 + 4];
        half2_t h;
        h[0] = (_Float16)w0;  h[1] = (_Float16)w1;  wp[dy*6+0] = __builtin_bit_cast(uint32_t, h);
        h[0] = (_Float16)w2v; h[1] = (_Float16)w3v; wp[dy*6+1] = __builtin_bit_cast(uint32_t, h);
        h[0] = (_Float16)w4;  h[1] = (_Float16)0.f; wp[dy*6+2] = __builtin_bit_cast(uint32_t, h);
        h[0] = (_Float16)0.f; h[1] = (_Float16)w0;  wp[dy*6+3] = __builtin_bit_cast(uint32_t, h);
        h[0] = (_Float16)w1;  h[1] = (_Float16)w2v; wp[dy*6+4] = __builtin_bit_cast(uint32_t, h);
        h[0] = (_Float16)w3v; h[1] = (_Float16)w4;  wp[dy*6+5] = __builtin_bit_cast(uint32_t, h);
    }
    wp[30] = 0; wp[31] = 0;
}

// ---- K7: conv3 5x5 — R13: 512 thr, 32x64 tile, 1y x 4x, 8-ch chunks ---------
// grid: 16 n * 8 yt * 4 xt = 512 blocks (2/CU, 16 waves/CU).
// LDS: 8ch x 36rows x 72cols f16 = 41472 B. Thread: 1y x 4x outputs.
__global__ __launch_bounds__(512, 4) void k_conv3(const int8_t* __restrict__ h2s,
                                                  const float* __restrict__ a2g,
                                                  const float* __restrict__ c2g,
                                                  const uint32_t* __restrict__ wtab,
                                                  float* __restrict__ out) {
    __shared__ uint16_t lds[8 * 36 * 72];       // ch stride 2592, row 72
    __shared__ float sA2[64], sC2[64];
    int t = threadIdx.x;
    int bid = blockIdx.x;                // 0..511
    int n  = bid >> 5;
    int yt = (bid >> 2) & 7;
    int xt = bid & 3;
    int ty0 = yt * 32, tx0 = xt * 64;
    if (t < 64) { sA2[t] = a2g[t]; sC2[t] = c2g[t]; }

    int ty = t >> 4, tx = t & 15;        // ty 0..31 (1 row), tx 0..15 (4 cols)
    int pbase = n * 64;

    // staging metadata: 8ch x 36rows x 17quads = 4896 items, 10 slots/thread
    int s_cl[10], s_lds[10];
    const int8_t* s_ptr[10];
    bool s_has[10], s_ok[10];
    #pragma unroll
    for (int it = 0; it < 10; ++it) {
        int si = t + 512 * it;
        int cl  = si / 612;              // 612 = 36*17, cl 0..7
        int rem = si - cl * 612;
        int row = rem / 17;
        int q   = rem - row * 17;
        int gy  = ty0 - 2 + row;
        bool has = (si < 4896);
        bool ok  = has && ((unsigned)gy < 256u);
        int clc = has ? cl : 0;
        s_cl[it]  = clc;
        s_lds[it] = clc * 2592 + row * 72 + q * 4;
        s_ptr[it] = h2s + (size_t)(pbase + clc) * PLANE_BYTES
                        + (size_t)(ok ? gy : 0) * ROW_BYTES + tx0 + q * 4;
        s_has[it] = has; s_ok[it] = ok;
    }
    int vv[10];
    #pragma unroll
    for (int it = 0; it < 10; ++it)
        vv[it] = s_ok[it] ? *(const int*)s_ptr[it] : 0;

    float acc[4] = {0.f, 0.f, 0.f, 0.f};

    for (int kk = 0; kk < 8; ++kk) {     // 8 chunks x 8 channels = 64 ch
        __syncthreads();                 // first iter also guards sA2/sC2
        #pragma unroll
        for (int it = 0; it < 10; ++it) {
            if (s_has[it]) {
                int lc = 8 * kk + s_cl[it];
                float a = sA2[lc], c = sC2[lc];
                int v = vv[it];
                float z0 = fmaf(a, (float)(int)(int8_t)(v),        c);
                float z1 = fmaf(a, (float)(int)(int8_t)(v >> 8),   c);
                float z2 = fmaf(a, (float)(int)(int8_t)(v >> 16),  c);
                float z3 = fmaf(a, (float)(int)(int8_t)(v >> 24),  c);
                z0 = fmaxf(z0, 0.5f * z0);
                z1 = fmaxf(z1, 0.5f * z1);
                z2 = fmaxf(z2, 0.5f * z2);
                z3 = fmaxf(z3, 0.5f * z3);
                uint2 wv2 = {pk_f16(z0, z1), pk_f16(z2, z3)};
                *(uint2*)(lds + s_lds[it]) = wv2;
            }
        }
        __syncthreads();
        if (kk < 7) {                    // prefetch next chunk (overlaps compute)
            #pragma unroll
            for (int it = 0; it < 10; ++it) {
                s_ptr[it] += 8 * PLANE_BYTES;
                vv[it] = s_ok[it] ? *(const int*)s_ptr[it] : 0;
            }
        }

        #pragma unroll
        for (int cl = 0; cl < 8; ++cl) {
            const uint32_t* wp = wtab + (size_t)(8 * kk + cl) * 32;   // uniform
            const uint16_t* base = lds + cl * 2592 + ty * 72 + 4 * tx;
            uint2 A[5], B[5];
            #pragma unroll
            for (int rr = 0; rr < 5; ++rr) {      // batched: 10 ds_read_b64
                A[rr] = *(const uint2*)(base + rr * 72);
                B[rr] = *(const uint2*)(base + rr * 72 + 4);
            }
            #pragma unroll
            for (int rr = 0; rr < 5; ++rr) {      // dyp == rr (single out row)
                half2_t W0 = H2(A[rr].x), W1 = H2(A[rr].y);
                half2_t W2 = H2(B[rr].x), W3 = H2(B[rr].y);
                const uint32_t* wd = wp + rr * 6;
                acc[0] = DOT2(W0, H2(wd[0]), DOT2(W1, H2(wd[1]), DOT2(W2, H2(wd[2]), acc[0])));
                acc[1] = DOT2(W0, H2(wd[3]), DOT2(W1, H2(wd[4]), DOT2(W2, H2(wd[5]), acc[1])));
                acc[2] = DOT2(W1, H2(wd[0]), DOT2(W2, H2(wd[1]), DOT2(W3, H2(wd[2]), acc[2])));
                acc[3] = DOT2(W1, H2(wd[3]), DOT2(W2, H2(wd[4]), DOT2(W3, H2(wd[5]), acc[3])));
            }
        }
    }

    int oy = ty0 + ty;
    int ox = tx0 + 4 * tx;
    float4 r = {acc[0], acc[1], acc[2], acc[3]};
    *(float4*)(out + (size_t)n * 65536 + (size_t)oy * 256 + ox) = r;
}

// ---------------------------------------------------------------------------
extern "C" void kernel_launch(void* const* d_in, const int* in_sizes, int n_in,
                              void* d_out, int out_size, void* d_ws, size_t ws_size,
                              hipStream_t stream) {
    const float* x  = (const float*)d_in[0];
    const float* w1 = (const float*)d_in[1];
    const float* g1 = (const float*)d_in[2];
    const float* b1 = (const float*)d_in[3];
    const float* w2 = (const float*)d_in[4];
    const float* g2 = (const float*)d_in[5];
    const float* b2 = (const float*)d_in[6];
    const float* w3 = (const float*)d_in[7];
    float* out = (float*)d_out;

    WS ws = carve(d_ws);

    k_pack_x<<<1024, 256, 0, stream>>>(x, ws.xbits);
    k_pack_w<<<1, 256, 0, stream>>>(w1, w2, ws.wb1, ws.w2lo, ws.w2hi, ws.w2pk,
                                    ws.st1, ws.st2);
    k_stats1<<<2048, 256, 0, stream>>>(ws.xbits, ws.wb1, ws.st1);
    k_fin1<<<1, 128, 0, stream>>>(ws.st1, g1, b1, ws.wb1, ws.pk1, ws.flipm);
    k_conv2<<<4096, 256, 0, stream>>>(ws.xbits, ws.pk1, ws.flipm, ws.w2pk, ws.h2s);
    k_stats2<<<1024, 256, 0, stream>>>(ws.h2s, ws.st2);
    k_fin2<<<1, 64, 0, stream>>>(ws.st2, g2, b2, w3, ws.a2, ws.c2, ws.wtab);
    k_conv3<<<512, 512, 0, stream>>>(ws.h2s, ws.a2, ws.c2, ws.wtab, out);
}

// Round 19
// 207.321 us; speedup vs baseline: 1.1876x; 1.0107x over previous
//
#include <hip/hip_runtime.h>
#include <cstdint>
#include <cstddef>
#include <climits>

// ---------------------------------------------------------------------------
// BNN pipeline:
//  L1: conv7x7(sign(x), sign(w1)) -> BN(train) -> leaky(0.5)
//  L2: conv1x1(sign(.), sign(w2)) -> BN(train) -> leaky(0.5)
//  L3: conv5x5 fp32 (64->1)
// Shapes: x (16,1,256,256), out (16,1,256,256)
//
// h2s layout (PADDED in x): int8 [16*64][256][264], col p maps to x = p-2.
//
// conv2: scalar-weight loads; wave-uniform interior fast path.
// conv3: R13 structure (A/B-proven best over 5 variants).
// stats1: 2 consecutive rows per block, ONE barrier phase (was 2 barriers
//         per row), fused channel loop over both rows, p-domain interior.
// ---------------------------------------------------------------------------

#define NPIX_PER_CH (16.0 * 256.0 * 256.0)
#define PLANE_BYTES 67584      // 256*264
#define ROW_BYTES   264

typedef _Float16 half2_t __attribute__((ext_vector_type(2)));

#if __has_builtin(__builtin_amdgcn_fdot2)
__device__ __forceinline__ float DOT2(half2_t a, half2_t b, float c) {
    return __builtin_amdgcn_fdot2(a, b, c, false);
}
#else
__device__ __forceinline__ float DOT2(half2_t a, half2_t b, float c) {
    return fmaf((float)a[0], (float)b[0], fmaf((float)a[1], (float)b[1], c));
}
#endif

__device__ __forceinline__ uint32_t pk_f16(float lo, float hi) {
#if __has_builtin(__builtin_amdgcn_cvt_pkrtz)
    auto h = __builtin_amdgcn_cvt_pkrtz(lo, hi);
    return __builtin_bit_cast(uint32_t, h);
#else
    half2_t h; h[0] = (_Float16)lo; h[1] = (_Float16)hi;
    return __builtin_bit_cast(uint32_t, h);
#endif
}
#define H2(u) __builtin_bit_cast(half2_t, (uint32_t)(u))

struct WS {
    int8_t*   h2s;
    uint64_t* xbits;
    uint64_t* wb1;
    uint64_t* w2lo;
    uint64_t* w2hi;
    uint4*    w2pk;               // [64]
    long long* st1;
    long long* st2;
    uint4*    pk1;                // [128] {wb_lo, wb_hi, K, pth}
    unsigned long long* flipm;    // [2]
    float* a2; float* c2;
    uint32_t* wtab;               // [64*32]
};

static inline WS carve(void* d_ws) {
    WS w;
    uint8_t* p = (uint8_t*)d_ws;
    w.h2s   = (int8_t*)p;              p += (size_t)16 * 64 * PLANE_BYTES;
    w.xbits = (uint64_t*)p;            p += (size_t)16 * 256 * 6 * 8;
    w.wb1   = (uint64_t*)p;            p += 128 * 8;
    w.w2lo  = (uint64_t*)p;            p += 64 * 8;
    w.w2hi  = (uint64_t*)p;            p += 64 * 8;
    w.w2pk  = (uint4*)p;               p += 64 * 16;
    w.st1   = (long long*)p;           p += 256 * 8;
    w.st2   = (long long*)p;           p += 128 * 8;
    w.pk1   = (uint4*)p;               p += 128 * 16;
    w.flipm = (unsigned long long*)p;  p += 2 * 8;
    w.a2    = (float*)p;               p += 64 * 4;
    w.c2    = (float*)p;               p += 64 * 4;
    w.wtab  = (uint32_t*)p;            p += 64 * 32 * 4;
    return w;
}

// ---- K0: pack sign bits of x into padded per-row words ---------------------
__global__ __launch_bounds__(256) void k_pack_x(const float* __restrict__ x,
                                                uint64_t* __restrict__ xbits) {
    int rowId = blockIdx.x * 4 + (threadIdx.x >> 6);
    int lane  = threadIdx.x & 63;
    const float* row = x + (size_t)rowId * 256;
    uint64_t b0 = __ballot(row[0 * 64 + lane] < 0.0f);
    uint64_t b1 = __ballot(row[1 * 64 + lane] < 0.0f);
    uint64_t b2 = __ballot(row[2 * 64 + lane] < 0.0f);
    uint64_t b3 = __ballot(row[3 * 64 + lane] < 0.0f);
    if (lane == 0) {
        uint64_t* o = xbits + (size_t)rowId * 6;
        o[0] = b0 << 8;
        o[1] = (b0 >> 56) | (b1 << 8);
        o[2] = (b1 >> 56) | (b2 << 8);
        o[3] = (b2 >> 56) | (b3 << 8);
        o[4] = b3 >> 56;
        o[5] = 0;
    }
}

// ---- K1: pack weight sign bits, zero stat accumulators ---------------------
__global__ void k_pack_w(const float* __restrict__ w1, const float* __restrict__ w2,
                         uint64_t* __restrict__ wb1, uint64_t* __restrict__ w2lo,
                         uint64_t* __restrict__ w2hi, uint4* __restrict__ w2pk,
                         long long* __restrict__ st1, long long* __restrict__ st2) {
    int t = threadIdx.x;
    if (t < 128) {
        uint64_t b = 0;
        for (int k = 0; k < 49; ++k)
            if (w1[t * 49 + k] < 0.0f) b |= (1ull << k);
        wb1[t] = b;
    } else if (t < 192) {
        int o = t - 128;
        uint64_t lo = 0, hi = 0;
        for (int c = 0; c < 64; ++c) if (w2[o * 128 + c]      < 0.0f) lo |= (1ull << c);
        for (int c = 0; c < 64; ++c) if (w2[o * 128 + 64 + c] < 0.0f) hi |= (1ull << c);
        w2lo[o] = lo; w2hi[o] = hi;
        w2pk[o] = make_uint4((uint32_t)lo, (uint32_t)(lo >> 32),
                             (uint32_t)hi, (uint32_t)(hi >> 32));
    }
    st1[t] = 0;
    if (t < 128) st2[t] = 0;
}

// ---- window builder: 49-bit sign window + validity mask --------------------
__device__ inline void build_window(const uint64_t* __restrict__ xb_img, int y, int x,
                                    uint64_t& sbits, uint64_t& vmask) {
    int bitpos = x + 5;
    int w  = bitpos >> 6;
    int sh = bitpos & 63;
    int lo = 3 - x;   if (lo < 0) lo = 0;
    int hi = 258 - x; if (hi > 6) hi = 6;
    uint64_t hm = ((1ull << (hi - lo + 1)) - 1ull) << lo;
    sbits = 0; vmask = 0;
    #pragma unroll
    for (int dy = 0; dy < 7; ++dy) {
        int yy = y - 3 + dy;
        if (yy < 0 || yy > 255) continue;
        const uint64_t* r = xb_img + (size_t)yy * 6;
        uint64_t wA = r[w], wB = r[w + 1];
        uint64_t bits = wA >> sh;
        if (sh) bits |= wB << (64 - sh);
        bits &= 0x7Full;
        sbits |= bits << (7 * dy);
        vmask |= hm   << (7 * dy);
    }
}

// ---- K2: layer-1 BN statistics; 2 rows/block, single barrier phase ----------
__global__ __launch_bounds__(256) void k_stats1(const uint64_t* __restrict__ xbits,
                                                const uint64_t* __restrict__ wb1g,
                                                long long* __restrict__ st1) {
    __shared__ uint64_t sb0[256], vm0[256];
    __shared__ uint64_t sb1[256], vm1[256];
    __shared__ int rs[128];
    __shared__ int rq[128];
    int t = threadIdx.x;
    int c = t & 127, half = t >> 7;
    uint64_t wb = wb1g[c];
    int sumE = 0, sqE = 0;
    int sumP = 0, sumPP = 0, nF = 0;

    int r0 = blockIdx.x * 2;             // even; rows r0, r0+1 (same image)
    int n = r0 >> 8, y0 = r0 & 255;
    const uint64_t* xb_img = xbits + (size_t)n * 256 * 6;
    uint64_t s0, v0, s1, v1;
    build_window(xb_img, y0,     t, s0, v0);
    build_window(xb_img, y0 + 1, t, s1, v1);
    sb0[t] = s0; vm0[t] = v0;
    sb1[t] = s1; vm1[t] = v1;
    __syncthreads();

    int base = half << 7;
    auto edge2 = [&](int p) {
        uint64_t vvA = vm0[base + p];
        uint64_t dA = (sb0[base + p] ^ wb) & vvA;
        int hA = __popcll(vvA) - 2 * __popcll(dA);
        sumE += hA; sqE += hA * hA;
        uint64_t vvB = vm1[base + p];
        uint64_t dB = (sb1[base + p] ^ wb) & vvB;
        int hB = __popcll(vvB) - 2 * __popcll(dB);
        sumE += hB; sqE += hB * hB;
    };
    bool bothInt = (y0 >= 3) && (y0 + 1 <= 252);
    if (bothInt) {
        int lo = (half == 0) ? 3 : 0;
        int hi = (half == 0) ? 128 : 125;
        for (int p = 0; p < lo; ++p) edge2(p);
        #pragma unroll 4
        for (int p = lo; p < hi; ++p) {
            int pc0 = __popcll(sb0[base + p] ^ wb);
            int pc1 = __popcll(sb1[base + p] ^ wb);
            sumP += pc0 + pc1;
            sumPP += pc0 * pc0 + pc1 * pc1;
        }
        for (int p = hi; p < 128; ++p) edge2(p);
        nF += 2 * (hi - lo);
    } else {
        #pragma unroll 4
        for (int p = 0; p < 128; ++p) edge2(p);
    }

    int sum   = sumE + 49 * nF - 2 * sumP;
    int sumsq = sqE + 2401 * nF - 196 * sumP + 4 * sumPP;
    __syncthreads();
    if (half == 1) { rs[c] = sum; rq[c] = sumsq; }
    __syncthreads();
    if (half == 0) {
        long long S = (long long)sum + rs[c];
        long long Q = (long long)sumsq + rq[c];
        atomicAdd((unsigned long long*)&st1[c],       (unsigned long long)S);
        atomicAdd((unsigned long long*)&st1[128 + c], (unsigned long long)Q);
    }
}

// ---- K3: BN1 -> {wb, K, pth} pack -------------------------------------------
__global__ void k_fin1(const long long* __restrict__ st1,
                       const float* __restrict__ g1, const float* __restrict__ b1,
                       const uint64_t* __restrict__ wb1,
                       uint4* __restrict__ pk1, unsigned long long* __restrict__ flipm) {
    int c = threadIdx.x;            // 128 threads
    double mean = (double)st1[c] / NPIX_PER_CH;
    double var  = (double)st1[128 + c] / NPIX_PER_CH - mean * mean;
    double a = (double)g1[c] / sqrt(var + 1e-5);
    double cst = (double)b1[c] - mean * a;
    int K; int flip = 0;
    if (a > 0.0) {
        double v = -cst / a;
        v = fmin(fmax(v, -100.0), 100.0);
        K = (int)ceil(v);
    } else if (a < 0.0) {
        double v = -cst / a;
        v = fmin(fmax(v, -100.0), 100.0);
        K = (int)floor(v) + 1; flip = 1;
    } else {
        K = INT_MIN; flip = (cst < 0.0) ? 1 : 0;
    }
    long long pt = ((49LL - (long long)K) >> 1) + 1;
    if (pt < 0) pt = 0;
    if (pt > 50) pt = 50;
    uint64_t wb = wb1[c];
    pk1[c] = make_uint4((uint32_t)wb, (uint32_t)(wb >> 32), (uint32_t)K, (uint32_t)pt);
    unsigned long long m = __ballot(flip != 0);
    if ((c & 63) == 0) flipm[c >> 6] = m;
}

// ---- K4: fused conv1-sign -> conv2 -> h2/2; wave-uniform fast path ----------
__global__ __launch_bounds__(256) void k_conv2(const uint64_t* __restrict__ xbits,
                                               const uint4* __restrict__ pk1,
                                               const unsigned long long* __restrict__ flipm,
                                               const uint4* __restrict__ w2pk,
                                               int8_t* __restrict__ h2s) {
    int t = threadIdx.x;
    int n = blockIdx.x >> 8, y = blockIdx.x & 255, x = t;
    const uint64_t* xb_img = xbits + (size_t)n * 256 * 6;
    uint64_t sbits, vmask;
    build_window(xb_img, y, x, sbits, vmask);
    int nv = __popcll(vmask);

    uint32_t bw0 = 0, bw1 = 0, bw2 = 0, bw3 = 0;
    int wvid = __builtin_amdgcn_readfirstlane(t >> 6);
    bool fastw = (y >= 3 && y <= 252) && (wvid == 1 || wvid == 2);
    if (fastw) {
        #pragma unroll
        for (int cc = 0; cc < 128; ++cc) {
            uint4 pk = pk1[cc];
            uint64_t wb = ((uint64_t)pk.y << 32) | pk.x;
            int pc = __popcll(sbits ^ wb);
            uint32_t b = (uint32_t)(pc >= (int)pk.w) << (cc & 31);
            if (cc < 32)       bw0 |= b;
            else if (cc < 64)  bw1 |= b;
            else if (cc < 96)  bw2 |= b;
            else               bw3 |= b;
        }
    } else {
        #pragma unroll
        for (int cc = 0; cc < 128; ++cc) {
            uint4 pk = pk1[cc];
            uint64_t wb = ((uint64_t)pk.y << 32) | pk.x;
            int h = nv - 2 * __popcll((sbits ^ wb) & vmask);
            uint32_t b = (uint32_t)(h < (int)pk.z) << (cc & 31);
            if (cc < 32)       bw0 |= b;
            else if (cc < 64)  bw1 |= b;
            else if (cc < 96)  bw2 |= b;
            else               bw3 |= b;
        }
    }
    unsigned long long f0 = flipm[0], f1 = flipm[1];
    bw0 ^= (uint32_t)f0; bw1 ^= (uint32_t)(f0 >> 32);
    bw2 ^= (uint32_t)f1; bw3 ^= (uint32_t)(f1 >> 32);

    size_t base = (size_t)(n * 64) * PLANE_BYTES + (size_t)y * ROW_BYTES;
    #pragma unroll
    for (int o = 0; o < 64; ++o) {
        uint4 w = w2pk[o];
        int m = __popc(bw0 ^ w.x) + __popc(bw1 ^ w.y)
              + __popc(bw2 ^ w.z) + __popc(bw3 ^ w.w);
        h2s[base + (size_t)o * PLANE_BYTES + 2 + x] = (int8_t)(64 - m);
    }
    if (x == 0) {
        #pragma unroll 8
        for (int o = 0; o < 64; ++o)
            *(short*)(h2s + base + (size_t)o * PLANE_BYTES) = 0;
    }
    if (x == 255) {
        #pragma unroll 8
        for (int o = 0; o < 64; ++o) {
            int8_t* r = h2s + base + (size_t)o * PLANE_BYTES;
            *(short*)(r + 258) = 0;
            *(int*)(r + 260) = 0;
        }
    }
}

// ---- K5: layer-2 BN statistics (on stored v = h2/2, padded layout) ----------
__global__ __launch_bounds__(256) void k_stats2(const int8_t* __restrict__ h2s,
                                                long long* __restrict__ st2) {
    int plane = blockIdx.x;       // n*64 + o
    int o = plane & 63;
    int t = threadIdx.x;
    const int4* p = (const int4*)(h2s + (size_t)plane * PLANE_BYTES);
    int sum = 0, sumsq = 0;
    for (int si = t; si < 4224; si += 256) {
        int4 v4 = p[si];
        int wv[4] = {v4.x, v4.y, v4.z, v4.w};
        #pragma unroll
        for (int j = 0; j < 4; ++j) {
            #pragma unroll
            for (int k = 0; k < 4; ++k) {
                int b = (int)(int8_t)((unsigned)wv[j] >> (8 * k));
                sum += b;
                sumsq += b * b;
            }
        }
    }
    for (int off = 32; off; off >>= 1) {
        sum   += __shfl_down(sum, off);
        sumsq += __shfl_down(sumsq, off);
    }
    __shared__ int ws1[4], ws2[4];
    int wid = t >> 6;
    if ((t & 63) == 0) { ws1[wid] = sum; ws2[wid] = sumsq; }
    __syncthreads();
    if (t == 0) {
        long long S = 0, Q = 0;
        for (int i = 0; i < 4; ++i) { S += ws1[i]; Q += ws2[i]; }
        atomicAdd((unsigned long long*)&st2[o],      (unsigned long long)S);
        atomicAdd((unsigned long long*)&st2[64 + o], (unsigned long long)Q);
    }
}

// ---- K6: BN2 coefficients + packed-f16 conv3 weight table -------------------
__global__ void k_fin2(const long long* __restrict__ st2,
                       const float* __restrict__ g2, const float* __restrict__ b2,
                       const float* __restrict__ w3,
                       float* __restrict__ a2, float* __restrict__ c2,
                       uint32_t* __restrict__ wtab) {
    int o = threadIdx.x;            // 64 threads
    double mean = 2.0 * (double)st2[o] / NPIX_PER_CH;
    double msq  = 4.0 * (double)st2[64 + o] / NPIX_PER_CH;
    double var  = msq - mean * mean;
    double inv  = (double)g2[o] / sqrt(var + 1e-5);
    a2[o] = (float)(2.0 * inv);
    c2[o] = (float)((double)b2[o] - mean * inv);

    uint32_t* wp = wtab + o * 32;
    #pragma unroll
    for (int dy = 0; dy < 5; ++dy) {
        float w0 = w3[o * 25 + dy * 5 + 0];
        float w1 = w3[o * 25 + dy * 5 + 1];
        float w2v = w3[o * 25 + dy * 5 + 2];
        float w3v = w3[o * 25 + dy * 5 + 3];
        float w4 = w3[o * 25 + dy * 5 + 4];
        half2_t h;
        h[0] = (_Float16)w0;  h[1] = (_Float16)w1;  wp[dy*6+0] = __builtin_bit_cast(uint32_t, h);
        h[0] = (_Float16)w2v; h[1] = (_Float16)w3v; wp[dy*6+1] = __builtin_bit_cast(uint32_t, h);
        h[0] = (_Float16)w4;  h[1] = (_Float16)0.f; wp[dy*6+2] = __builtin_bit_cast(uint32_t, h);
        h[0] = (_Float16)0.f; h[1] = (_Float16)w0;  wp[dy*6+3] = __builtin_bit_cast(uint32_t, h);
        h[0] = (_Float16)w1;  h[1] = (_Float16)w2v; wp[dy*6+4] = __builtin_bit_cast(uint32_t, h);
        h[0] = (_Float16)w3v; h[1] = (_Float16)w4;  wp[dy*6+5] = __builtin_bit_cast(uint32_t, h);
    }
    wp[30] = 0; wp[31] = 0;
}

// ---- K7: conv3 5x5 — R13: 512 thr, 32x64 tile, 1y x 4x, 8-ch chunks ---------
// grid: 16 n * 8 yt * 4 xt = 512 blocks (2/CU, 16 waves/CU).
// LDS: 8ch x 36rows x 72cols f16 = 41472 B. Thread: 1y x 4x outputs.
__global__ __launch_bounds__(512, 4) void k_conv3(const int8_t* __restrict__ h2s,
                                                  const float* __restrict__ a2g,
                                                  const float* __restrict__ c2g,
                                                  const uint32_t* __restrict__ wtab,
                                                  float* __restrict__ out) {
    __shared__ uint16_t lds[8 * 36 * 72];       // ch stride 2592, row 72
    __shared__ float sA2[64], sC2[64];
    int t = threadIdx.x;
    int bid = blockIdx.x;                // 0..511
    int n  = bid >> 5;
    int yt = (bid >> 2) & 7;
    int xt = bid & 3;
    int ty0 = yt * 32, tx0 = xt * 64;
    if (t < 64) { sA2[t] = a2g[t]; sC2[t] = c2g[t]; }

    int ty = t >> 4, tx = t & 15;        // ty 0..31 (1 row), tx 0..15 (4 cols)
    int pbase = n * 64;

    // staging metadata: 8ch x 36rows x 17quads = 4896 items, 10 slots/thread
    int s_cl[10], s_lds[10];
    const int8_t* s_ptr[10];
    bool s_has[10], s_ok[10];
    #pragma unroll
    for (int it = 0; it < 10; ++it) {
        int si = t + 512 * it;
        int cl  = si / 612;              // 612 = 36*17, cl 0..7
        int rem = si - cl * 612;
        int row = rem / 17;
        int q   = rem - row * 17;
        int gy  = ty0 - 2 + row;
        bool has = (si < 4896);
        bool ok  = has && ((unsigned)gy < 256u);
        int clc = has ? cl : 0;
        s_cl[it]  = clc;
        s_lds[it] = clc * 2592 + row * 72 + q * 4;
        s_ptr[it] = h2s + (size_t)(pbase + clc) * PLANE_BYTES
                        + (size_t)(ok ? gy : 0) * ROW_BYTES + tx0 + q * 4;
        s_has[it] = has; s_ok[it] = ok;
    }
    int vv[10];
    #pragma unroll
    for (int it = 0; it < 10; ++it)
        vv[it] = s_ok[it] ? *(const int*)s_ptr[it] : 0;

    float acc[4] = {0.f, 0.f, 0.f, 0.f};

    for (int kk = 0; kk < 8; ++kk) {     // 8 chunks x 8 channels = 64 ch
        __syncthreads();                 // first iter also guards sA2/sC2
        #pragma unroll
        for (int it = 0; it < 10; ++it) {
            if (s_has[it]) {
                int lc = 8 * kk + s_cl[it];
                float a = sA2[lc], c = sC2[lc];
                int v = vv[it];
                float z0 = fmaf(a, (float)(int)(int8_t)(v),        c);
                float z1 = fmaf(a, (float)(int)(int8_t)(v >> 8),   c);
                float z2 = fmaf(a, (float)(int)(int8_t)(v >> 16),  c);
                float z3 = fmaf(a, (float)(int)(int8_t)(v >> 24),  c);
                z0 = fmaxf(z0, 0.5f * z0);
                z1 = fmaxf(z1, 0.5f * z1);
                z2 = fmaxf(z2, 0.5f * z2);
                z3 = fmaxf(z3, 0.5f * z3);
                uint2 wv2 = {pk_f16(z0, z1), pk_f16(z2, z3)};
                *(uint2*)(lds + s_lds[it]) = wv2;
            }
        }
        __syncthreads();
        if (kk < 7) {                    // prefetch next chunk (overlaps compute)
            #pragma unroll
            for (int it = 0; it < 10; ++it) {
                s_ptr[it] += 8 * PLANE_BYTES;
                vv[it] = s_ok[it] ? *(const int*)s_ptr[it] : 0;
            }
        }

        #pragma unroll
        for (int cl = 0; cl < 8; ++cl) {
            const uint32_t* wp = wtab + (size_t)(8 * kk + cl) * 32;   // uniform
            const uint16_t* base = lds + cl * 2592 + ty * 72 + 4 * tx;
            uint2 A[5], B[5];
            #pragma unroll
            for (int rr = 0; rr < 5; ++rr) {      // batched: 10 ds_read_b64
                A[rr] = *(const uint2*)(base + rr * 72);
                B[rr] = *(const uint2*)(base + rr * 72 + 4);
            }
            #pragma unroll
            for (int rr = 0; rr < 5; ++rr) {      // dyp == rr (single out row)
                half2_t W0 = H2(A[rr].x), W1 = H2(A[rr].y);
                half2_t W2 = H2(B[rr].x), W3 = H2(B[rr].y);
                const uint32_t* wd = wp + rr * 6;
                acc[0] = DOT2(W0, H2(wd[0]), DOT2(W1, H2(wd[1]), DOT2(W2, H2(wd[2]), acc[0])));
                acc[1] = DOT2(W0, H2(wd[3]), DOT2(W1, H2(wd[4]), DOT2(W2, H2(wd[5]), acc[1])));
                acc[2] = DOT2(W1, H2(wd[0]), DOT2(W2, H2(wd[1]), DOT2(W3, H2(wd[2]), acc[2])));
                acc[3] = DOT2(W1, H2(wd[3]), DOT2(W2, H2(wd[4]), DOT2(W3, H2(wd[5]), acc[3])));
            }
        }
    }

    int oy = ty0 + ty;
    int ox = tx0 + 4 * tx;
    float4 r = {acc[0], acc[1], acc[2], acc[3]};
    *(float4*)(out + (size_t)n * 65536 + (size_t)oy * 256 + ox) = r;
}

// ---------------------------------------------------------------------------
extern "C" void kernel_launch(void* const* d_in, const int* in_sizes, int n_in,
                              void* d_out, int out_size, void* d_ws, size_t ws_size,
                              hipStream_t stream) {
    const float* x  = (const float*)d_in[0];
    const float* w1 = (const float*)d_in[1];
    const float* g1 = (const float*)d_in[2];
    const float* b1 = (const float*)d_in[3];
    const float* w2 = (const float*)d_in[4];
    const float* g2 = (const float*)d_in[5];
    const float* b2 = (const float*)d_in[6];
    const float* w3 = (const float*)d_in[7];
    float* out = (float*)d_out;

    WS ws = carve(d_ws);

    k_pack_x<<<1024, 256, 0, stream>>>(x, ws.xbits);
    k_pack_w<<<1, 256, 0, stream>>>(w1, w2, ws.wb1, ws.w2lo, ws.w2hi, ws.w2pk,
                                    ws.st1, ws.st2);
    k_stats1<<<2048, 256, 0, stream>>>(ws.xbits, ws.wb1, ws.st1);
    k_fin1<<<1, 128, 0, stream>>>(ws.st1, g1, b1, ws.wb1, ws.pk1, ws.flipm);
    k_conv2<<<4096, 256, 0, stream>>>(ws.xbits, ws.pk1, ws.flipm, ws.w2pk, ws.h2s);
    k_stats2<<<1024, 256, 0, stream>>>(ws.h2s, ws.st2);
    k_fin2<<<1, 64, 0, stream>>>(ws.st2, g2, b2, w3, ws.a2, ws.c2, ws.wtab);
    k_conv3<<<512, 512, 0, stream>>>(ws.h2s, ws.a2, ws.c2, ws.wtab, out);
}

// Round 20
// 206.272 us; speedup vs baseline: 1.1936x; 1.0051x over previous
//
#include <hip/hip_runtime.h>
#include <cstdint>
#include <cstddef>
#include <climits>

// ---------------------------------------------------------------------------
// BNN pipeline:
//  L1: conv7x7(sign(x), sign(w1)) -> BN(train) -> leaky(0.5)
//  L2: conv1x1(sign(.), sign(w2)) -> BN(train) -> leaky(0.5)
//  L3: conv5x5 fp32 (64->1)
// Shapes: x (16,1,256,256), out (16,1,256,256)
//
// h2s layout (PADDED in x): int8 [16*64][256][264], col p maps to x = p-2.
//
// conv2: scalar-weight loads; wave-uniform interior fast path.
// conv3: R13 structure (A/B-proven best over 5 variants).
// stats1: 2 rows/block; BOTH windows packed into one 63-bit word (9 strips
//         x 7 bits) -> interior loop does 1 ds_read_b64 (was 2) feeding two
//         independent popcount chains. p-domain interior, exact edge path.
// ---------------------------------------------------------------------------

#define NPIX_PER_CH (16.0 * 256.0 * 256.0)
#define PLANE_BYTES 67584      // 256*264
#define ROW_BYTES   264

typedef _Float16 half2_t __attribute__((ext_vector_type(2)));

#if __has_builtin(__builtin_amdgcn_fdot2)
__device__ __forceinline__ float DOT2(half2_t a, half2_t b, float c) {
    return __builtin_amdgcn_fdot2(a, b, c, false);
}
#else
__device__ __forceinline__ float DOT2(half2_t a, half2_t b, float c) {
    return fmaf((float)a[0], (float)b[0], fmaf((float)a[1], (float)b[1], c));
}
#endif

__device__ __forceinline__ uint32_t pk_f16(float lo, float hi) {
#if __has_builtin(__builtin_amdgcn_cvt_pkrtz)
    auto h = __builtin_amdgcn_cvt_pkrtz(lo, hi);
    return __builtin_bit_cast(uint32_t, h);
#else
    half2_t h; h[0] = (_Float16)lo; h[1] = (_Float16)hi;
    return __builtin_bit_cast(uint32_t, h);
#endif
}
#define H2(u) __builtin_bit_cast(half2_t, (uint32_t)(u))

struct WS {
    int8_t*   h2s;
    uint64_t* xbits;
    uint64_t* wb1;
    uint64_t* w2lo;
    uint64_t* w2hi;
    uint4*    w2pk;               // [64]
    long long* st1;
    long long* st2;
    uint4*    pk1;                // [128] {wb_lo, wb_hi, K, pth}
    unsigned long long* flipm;    // [2]
    float* a2; float* c2;
    uint32_t* wtab;               // [64*32]
};

static inline WS carve(void* d_ws) {
    WS w;
    uint8_t* p = (uint8_t*)d_ws;
    w.h2s   = (int8_t*)p;              p += (size_t)16 * 64 * PLANE_BYTES;
    w.xbits = (uint64_t*)p;            p += (size_t)16 * 256 * 6 * 8;
    w.wb1   = (uint64_t*)p;            p += 128 * 8;
    w.w2lo  = (uint64_t*)p;            p += 64 * 8;
    w.w2hi  = (uint64_t*)p;            p += 64 * 8;
    w.w2pk  = (uint4*)p;               p += 64 * 16;
    w.st1   = (long long*)p;           p += 256 * 8;
    w.st2   = (long long*)p;           p += 128 * 8;
    w.pk1   = (uint4*)p;               p += 128 * 16;
    w.flipm = (unsigned long long*)p;  p += 2 * 8;
    w.a2    = (float*)p;               p += 64 * 4;
    w.c2    = (float*)p;               p += 64 * 4;
    w.wtab  = (uint32_t*)p;            p += 64 * 32 * 4;
    return w;
}

// ---- K0: pack sign bits of x into padded per-row words ---------------------
__global__ __launch_bounds__(256) void k_pack_x(const float* __restrict__ x,
                                                uint64_t* __restrict__ xbits) {
    int rowId = blockIdx.x * 4 + (threadIdx.x >> 6);
    int lane  = threadIdx.x & 63;
    const float* row = x + (size_t)rowId * 256;
    uint64_t b0 = __ballot(row[0 * 64 + lane] < 0.0f);
    uint64_t b1 = __ballot(row[1 * 64 + lane] < 0.0f);
    uint64_t b2 = __ballot(row[2 * 64 + lane] < 0.0f);
    uint64_t b3 = __ballot(row[3 * 64 + lane] < 0.0f);
    if (lane == 0) {
        uint64_t* o = xbits + (size_t)rowId * 6;
        o[0] = b0 << 8;
        o[1] = (b0 >> 56) | (b1 << 8);
        o[2] = (b1 >> 56) | (b2 << 8);
        o[3] = (b2 >> 56) | (b3 << 8);
        o[4] = b3 >> 56;
        o[5] = 0;
    }
}

// ---- K1: pack weight sign bits, zero stat accumulators ---------------------
__global__ void k_pack_w(const float* __restrict__ w1, const float* __restrict__ w2,
                         uint64_t* __restrict__ wb1, uint64_t* __restrict__ w2lo,
                         uint64_t* __restrict__ w2hi, uint4* __restrict__ w2pk,
                         long long* __restrict__ st1, long long* __restrict__ st2) {
    int t = threadIdx.x;
    if (t < 128) {
        uint64_t b = 0;
        for (int k = 0; k < 49; ++k)
            if (w1[t * 49 + k] < 0.0f) b |= (1ull << k);
        wb1[t] = b;
    } else if (t < 192) {
        int o = t - 128;
        uint64_t lo = 0, hi = 0;
        for (int c = 0; c < 64; ++c) if (w2[o * 128 + c]      < 0.0f) lo |= (1ull << c);
        for (int c = 0; c < 64; ++c) if (w2[o * 128 + 64 + c] < 0.0f) hi |= (1ull << c);
        w2lo[o] = lo; w2hi[o] = hi;
        w2pk[o] = make_uint4((uint32_t)lo, (uint32_t)(lo >> 32),
                             (uint32_t)hi, (uint32_t)(hi >> 32));
    }
    st1[t] = 0;
    if (t < 128) st2[t] = 0;
}

// ---- window builder: 49-bit sign window + validity mask --------------------
__device__ inline void build_window(const uint64_t* __restrict__ xb_img, int y, int x,
                                    uint64_t& sbits, uint64_t& vmask) {
    int bitpos = x + 5;
    int w  = bitpos >> 6;
    int sh = bitpos & 63;
    int lo = 3 - x;   if (lo < 0) lo = 0;
    int hi = 258 - x; if (hi > 6) hi = 6;
    uint64_t hm = ((1ull << (hi - lo + 1)) - 1ull) << lo;
    sbits = 0; vmask = 0;
    #pragma unroll
    for (int dy = 0; dy < 7; ++dy) {
        int yy = y - 3 + dy;
        if (yy < 0 || yy > 255) continue;
        const uint64_t* r = xb_img + (size_t)yy * 6;
        uint64_t wA = r[w], wB = r[w + 1];
        uint64_t bits = wA >> sh;
        if (sh) bits |= wB << (64 - sh);
        bits &= 0x7Full;
        sbits |= bits << (7 * dy);
        vmask |= hm   << (7 * dy);
    }
}

// ---- K2: layer-1 BN stats; 2 rows/block, packed 9-strip windows -------------
// pk[x] bits [7*dy .. 7*dy+6] = sign strip of row y0-3+dy (dy 0..8).
// window(y0)   = pk & M49 ; window(y0+1) = (pk >> 7) & M49.
__global__ __launch_bounds__(256) void k_stats1(const uint64_t* __restrict__ xbits,
                                                const uint64_t* __restrict__ wb1g,
                                                long long* __restrict__ st1) {
    __shared__ uint64_t pkw[256];
    __shared__ uint64_t vm0[256], vm1[256];
    __shared__ int rs[128];
    __shared__ int rq[128];
    const uint64_t M  = (1ull << 49) - 1;
    const uint64_t M7 = M << 7;
    int t = threadIdx.x;
    int c = t & 127, half = t >> 7;
    uint64_t wb = wb1g[c];
    uint64_t wb7 = wb << 7;
    int sumE = 0, sqE = 0;
    int sumP = 0, sumPP = 0, nF = 0;

    int r0 = blockIdx.x * 2;             // even; rows r0, r0+1 (same image)
    int n = r0 >> 8, y0 = r0 & 255;
    const uint64_t* xb_img = xbits + (size_t)n * 256 * 6;
    {   // build packed word + the two validity masks for pixel x = t
        int x = t;
        int bitpos = x + 5;
        int w = bitpos >> 6, sh = bitpos & 63;
        int lo = 3 - x;   if (lo < 0) lo = 0;
        int hi = 258 - x; if (hi > 6) hi = 6;
        uint64_t hm = ((1ull << (hi - lo + 1)) - 1ull) << lo;
        uint64_t pv = 0, v0 = 0, v1 = 0;
        #pragma unroll
        for (int dy = 0; dy < 9; ++dy) {
            int yy = y0 - 3 + dy;
            if (yy >= 0 && yy <= 255) {
                const uint64_t* r = xb_img + (size_t)yy * 6;
                uint64_t bits = r[w] >> sh;
                if (sh) bits |= r[w + 1] << (64 - sh);
                bits &= 0x7Full;
                pv |= bits << (7 * dy);
                if (dy <= 6) v0 |= hm << (7 * dy);            // window y0
                if (dy >= 1 && dy <= 7) v1 |= hm << (7 * (dy - 1)); // window y0+1
            }
        }
        pkw[t] = pv; vm0[t] = v0; vm1[t] = v1;
    }
    __syncthreads();

    int base = half << 7;
    auto edge2 = [&](int p) {
        uint64_t v = pkw[base + p];
        uint64_t vvA = vm0[base + p];
        int hA = __popcll(vvA) - 2 * __popcll((v ^ wb) & vvA);
        sumE += hA; sqE += hA * hA;
        uint64_t vvB = vm1[base + p];
        int hB = __popcll(vvB) - 2 * __popcll(((v >> 7) ^ wb) & vvB);
        sumE += hB; sqE += hB * hB;
    };
    bool bothInt = (y0 >= 3) && (y0 + 1 <= 252);
    if (bothInt) {
        int lo = (half == 0) ? 3 : 0;
        int hi = (half == 0) ? 128 : 125;
        for (int p = 0; p < lo; ++p) edge2(p);
        #pragma unroll 8
        for (int p = lo; p < hi; ++p) {
            uint64_t v = pkw[base + p];
            int pc0 = __popcll((v ^ wb) & M);
            int pc1 = __popcll((v ^ wb7) & M7);
            sumP += pc0 + pc1;
            sumPP += pc0 * pc0 + pc1 * pc1;
        }
        for (int p = hi; p < 128; ++p) edge2(p);
        nF += 2 * (hi - lo);
    } else {
        #pragma unroll 4
        for (int p = 0; p < 128; ++p) edge2(p);
    }

    int sum   = sumE + 49 * nF - 2 * sumP;
    int sumsq = sqE + 2401 * nF - 196 * sumP + 4 * sumPP;
    __syncthreads();
    if (half == 1) { rs[c] = sum; rq[c] = sumsq; }
    __syncthreads();
    if (half == 0) {
        long long S = (long long)sum + rs[c];
        long long Q = (long long)sumsq + rq[c];
        atomicAdd((unsigned long long*)&st1[c],       (unsigned long long)S);
        atomicAdd((unsigned long long*)&st1[128 + c], (unsigned long long)Q);
    }
}

// ---- K3: BN1 -> {wb, K, pth} pack -------------------------------------------
__global__ void k_fin1(const long long* __restrict__ st1,
                       const float* __restrict__ g1, const float* __restrict__ b1,
                       const uint64_t* __restrict__ wb1,
                       uint4* __restrict__ pk1, unsigned long long* __restrict__ flipm) {
    int c = threadIdx.x;            // 128 threads
    double mean = (double)st1[c] / NPIX_PER_CH;
    double var  = (double)st1[128 + c] / NPIX_PER_CH - mean * mean;
    double a = (double)g1[c] / sqrt(var + 1e-5);
    double cst = (double)b1[c] - mean * a;
    int K; int flip = 0;
    if (a > 0.0) {
        double v = -cst / a;
        v = fmin(fmax(v, -100.0), 100.0);
        K = (int)ceil(v);
    } else if (a < 0.0) {
        double v = -cst / a;
        v = fmin(fmax(v, -100.0), 100.0);
        K = (int)floor(v) + 1; flip = 1;
    } else {
        K = INT_MIN; flip = (cst < 0.0) ? 1 : 0;
    }
    long long pt = ((49LL - (long long)K) >> 1) + 1;
    if (pt < 0) pt = 0;
    if (pt > 50) pt = 50;
    uint64_t wb = wb1[c];
    pk1[c] = make_uint4((uint32_t)wb, (uint32_t)(wb >> 32), (uint32_t)K, (uint32_t)pt);
    unsigned long long m = __ballot(flip != 0);
    if ((c & 63) == 0) flipm[c >> 6] = m;
}

// ---- K4: fused conv1-sign -> conv2 -> h2/2; wave-uniform fast path ----------
__global__ __launch_bounds__(256) void k_conv2(const uint64_t* __restrict__ xbits,
                                               const uint4* __restrict__ pk1,
                                               const unsigned long long* __restrict__ flipm,
                                               const uint4* __restrict__ w2pk,
                                               int8_t* __restrict__ h2s) {
    int t = threadIdx.x;
    int n = blockIdx.x >> 8, y = blockIdx.x & 255, x = t;
    const uint64_t* xb_img = xbits + (size_t)n * 256 * 6;
    uint64_t sbits, vmask;
    build_window(xb_img, y, x, sbits, vmask);
    int nv = __popcll(vmask);

    uint32_t bw0 = 0, bw1 = 0, bw2 = 0, bw3 = 0;
    int wvid = __builtin_amdgcn_readfirstlane(t >> 6);
    bool fastw = (y >= 3 && y <= 252) && (wvid == 1 || wvid == 2);
    if (fastw) {
        #pragma unroll
        for (int cc = 0; cc < 128; ++cc) {
            uint4 pk = pk1[cc];
            uint64_t wb = ((uint64_t)pk.y << 32) | pk.x;
            int pc = __popcll(sbits ^ wb);
            uint32_t b = (uint32_t)(pc >= (int)pk.w) << (cc & 31);
            if (cc < 32)       bw0 |= b;
            else if (cc < 64)  bw1 |= b;
            else if (cc < 96)  bw2 |= b;
            else               bw3 |= b;
        }
    } else {
        #pragma unroll
        for (int cc = 0; cc < 128; ++cc) {
            uint4 pk = pk1[cc];
            uint64_t wb = ((uint64_t)pk.y << 32) | pk.x;
            int h = nv - 2 * __popcll((sbits ^ wb) & vmask);
            uint32_t b = (uint32_t)(h < (int)pk.z) << (cc & 31);
            if (cc < 32)       bw0 |= b;
            else if (cc < 64)  bw1 |= b;
            else if (cc < 96)  bw2 |= b;
            else               bw3 |= b;
        }
    }
    unsigned long long f0 = flipm[0], f1 = flipm[1];
    bw0 ^= (uint32_t)f0; bw1 ^= (uint32_t)(f0 >> 32);
    bw2 ^= (uint32_t)f1; bw3 ^= (uint32_t)(f1 >> 32);

    size_t base = (size_t)(n * 64) * PLANE_BYTES + (size_t)y * ROW_BYTES;
    #pragma unroll
    for (int o = 0; o < 64; ++o) {
        uint4 w = w2pk[o];
        int m = __popc(bw0 ^ w.x) + __popc(bw1 ^ w.y)
              + __popc(bw2 ^ w.z) + __popc(bw3 ^ w.w);
        h2s[base + (size_t)o * PLANE_BYTES + 2 + x] = (int8_t)(64 - m);
    }
    if (x == 0) {
        #pragma unroll 8
        for (int o = 0; o < 64; ++o)
            *(short*)(h2s + base + (size_t)o * PLANE_BYTES) = 0;
    }
    if (x == 255) {
        #pragma unroll 8
        for (int o = 0; o < 64; ++o) {
            int8_t* r = h2s + base + (size_t)o * PLANE_BYTES;
            *(short*)(r + 258) = 0;
            *(int*)(r + 260) = 0;
        }
    }
}

// ---- K5: layer-2 BN statistics (on stored v = h2/2, padded layout) ----------
__global__ __launch_bounds__(256) void k_stats2(const int8_t* __restrict__ h2s,
                                                long long* __restrict__ st2) {
    int plane = blockIdx.x;       // n*64 + o
    int o = plane & 63;
    int t = threadIdx.x;
    const int4* p = (const int4*)(h2s + (size_t)plane * PLANE_BYTES);
    int sum = 0, sumsq = 0;
    for (int si = t; si < 4224; si += 256) {
        int4 v4 = p[si];
        int wv[4] = {v4.x, v4.y, v4.z, v4.w};
        #pragma unroll
        for (int j = 0; j < 4; ++j) {
            #pragma unroll
            for (int k = 0; k < 4; ++k) {
                int b = (int)(int8_t)((unsigned)wv[j] >> (8 * k));
                sum += b;
                sumsq += b * b;
            }
        }
    }
    for (int off = 32; off; off >>= 1) {
        sum   += __shfl_down(sum, off);
        sumsq += __shfl_down(sumsq, off);
    }
    __shared__ int ws1[4], ws2[4];
    int wid = t >> 6;
    if ((t & 63) == 0) { ws1[wid] = sum; ws2[wid] = sumsq; }
    __syncthreads();
    if (t == 0) {
        long long S = 0, Q = 0;
        for (int i = 0; i < 4; ++i) { S += ws1[i]; Q += ws2[i]; }
        atomicAdd((unsigned long long*)&st2[o],      (unsigned long long)S);
        atomicAdd((unsigned long long*)&st2[64 + o], (unsigned long long)Q);
    }
}

// ---- K6: BN2 coefficients + packed-f16 conv3 weight table -------------------
__global__ void k_fin2(const long long* __restrict__ st2,
                       const float* __restrict__ g2, const float* __restrict__ b2,
                       const float* __restrict__ w3,
                       float* __restrict__ a2, float* __restrict__ c2,
                       uint32_t* __restrict__ wtab) {
    int o = threadIdx.x;            // 64 threads
    double mean = 2.0 * (double)st2[o] / NPIX_PER_CH;
    double msq  = 4.0 * (double)st2[64 + o] / NPIX_PER_CH;
    double var  = msq - mean * mean;
    double inv  = (double)g2[o] / sqrt(var + 1e-5);
    a2[o] = (float)(2.0 * inv);
    c2[o] = (float)((double)b2[o] - mean * inv);

    uint32_t* wp = wtab + o * 32;
    #pragma unroll
    for (int dy = 0; dy < 5; ++dy) {
        float w0 = w3[o * 25 + dy * 5 + 0];
        float w1 = w3[o * 25 + dy * 5 + 1];
        float w2v = w3[o * 25 + dy * 5 + 2];
        float w3v = w3[o * 25 + dy * 5 + 3];
        float w4 = w3[o * 25 + dy * 5 + 4];
        half2_t h;
        h[0] = (_Float16)w0;  h[1] = (_Float16)w1;  wp[dy*6+0] = __builtin_bit_cast(uint32_t, h);
        h[0] = (_Float16)w2v; h[1] = (_Float16)w3v; wp[dy*6+1] = __builtin_bit_cast(uint32_t, h);
        h[0] = (_Float16)w4;  h[1] = (_Float16)0.f; wp[dy*6+2] = __builtin_bit_cast(uint32_t, h);
        h[0] = (_Float16)0.f; h[1] = (_Float16)w0;  wp[dy*6+3] = __builtin_bit_cast(uint32_t, h);
        h[0] = (_Float16)w1;  h[1] = (_Float16)w2v; wp[dy*6+4] = __builtin_bit_cast(uint32_t, h);
        h[0] = (_Float16)w3v; h[1] = (_Float16)w4;  wp[dy*6+5] = __builtin_bit_cast(uint32_t, h);
    }
    wp[30] = 0; wp[31] = 0;
}

// ---- K7: conv3 5x5 — R13: 512 thr, 32x64 tile, 1y x 4x, 8-ch chunks ---------
// grid: 16 n * 8 yt * 4 xt = 512 blocks (2/CU, 16 waves/CU).
// LDS: 8ch x 36rows x 72cols f16 = 41472 B. Thread: 1y x 4x outputs.
__global__ __launch_bounds__(512, 4) void k_conv3(const int8_t* __restrict__ h2s,
                                                  const float* __restrict__ a2g,
                                                  const float* __restrict__ c2g,
                                                  const uint32_t* __restrict__ wtab,
                                                  float* __restrict__ out) {
    __shared__ uint16_t lds[8 * 36 * 72];       // ch stride 2592, row 72
    __shared__ float sA2[64], sC2[64];
    int t = threadIdx.x;
    int bid = blockIdx.x;                // 0..511
    int n  = bid >> 5;
    int yt = (bid >> 2) & 7;
    int xt = bid & 3;
    int ty0 = yt * 32, tx0 = xt * 64;
    if (t < 64) { sA2[t] = a2g[t]; sC2[t] = c2g[t]; }

    int ty = t >> 4, tx = t & 15;        // ty 0..31 (1 row), tx 0..15 (4 cols)
    int pbase = n * 64;

    // staging metadata: 8ch x 36rows x 17quads = 4896 items, 10 slots/thread
    int s_cl[10], s_lds[10];
    const int8_t* s_ptr[10];
    bool s_has[10], s_ok[10];
    #pragma unroll
    for (int it = 0; it < 10; ++it) {
        int si = t + 512 * it;
        int cl  = si / 612;              // 612 = 36*17, cl 0..7
        int rem = si - cl * 612;
        int row = rem / 17;
        int q   = rem - row * 17;
        int gy  = ty0 - 2 + row;
        bool has = (si < 4896);
        bool ok  = has && ((unsigned)gy < 256u);
        int clc = has ? cl : 0;
        s_cl[it]  = clc;
        s_lds[it] = clc * 2592 + row * 72 + q * 4;
        s_ptr[it] = h2s + (size_t)(pbase + clc) * PLANE_BYTES
                        + (size_t)(ok ? gy : 0) * ROW_BYTES + tx0 + q * 4;
        s_has[it] = has; s_ok[it] = ok;
    }
    int vv[10];
    #pragma unroll
    for (int it = 0; it < 10; ++it)
        vv[it] = s_ok[it] ? *(const int*)s_ptr[it] : 0;

    float acc[4] = {0.f, 0.f, 0.f, 0.f};

    for (int kk = 0; kk < 8; ++kk) {     // 8 chunks x 8 channels = 64 ch
        __syncthreads();                 // first iter also guards sA2/sC2
        #pragma unroll
        for (int it = 0; it < 10; ++it) {
            if (s_has[it]) {
                int lc = 8 * kk + s_cl[it];
                float a = sA2[lc], c = sC2[lc];
                int v = vv[it];
                float z0 = fmaf(a, (float)(int)(int8_t)(v),        c);
                float z1 = fmaf(a, (float)(int)(int8_t)(v >> 8),   c);
                float z2 = fmaf(a, (float)(int)(int8_t)(v >> 16),  c);
                float z3 = fmaf(a, (float)(int)(int8_t)(v >> 24),  c);
                z0 = fmaxf(z0, 0.5f * z0);
                z1 = fmaxf(z1, 0.5f * z1);
                z2 = fmaxf(z2, 0.5f * z2);
                z3 = fmaxf(z3, 0.5f * z3);
                uint2 wv2 = {pk_f16(z0, z1), pk_f16(z2, z3)};
                *(uint2*)(lds + s_lds[it]) = wv2;
            }
        }
        __syncthreads();
        if (kk < 7) {                    // prefetch next chunk (overlaps compute)
            #pragma unroll
            for (int it = 0; it < 10; ++it) {
                s_ptr[it] += 8 * PLANE_BYTES;
                vv[it] = s_ok[it] ? *(const int*)s_ptr[it] : 0;
            }
        }

        #pragma unroll
        for (int cl = 0; cl < 8; ++cl) {
            const uint32_t* wp = wtab + (size_t)(8 * kk + cl) * 32;   // uniform
            const uint16_t* base = lds + cl * 2592 + ty * 72 + 4 * tx;
            uint2 A[5], B[5];
            #pragma unroll
            for (int rr = 0; rr < 5; ++rr) {      // batched: 10 ds_read_b64
                A[rr] = *(const uint2*)(base + rr * 72);
                B[rr] = *(const uint2*)(base + rr * 72 + 4);
            }
            #pragma unroll
            for (int rr = 0; rr < 5; ++rr) {      // dyp == rr (single out row)
                half2_t W0 = H2(A[rr].x), W1 = H2(A[rr].y);
                half2_t W2 = H2(B[rr].x), W3 = H2(B[rr].y);
                const uint32_t* wd = wp + rr * 6;
                acc[0] = DOT2(W0, H2(wd[0]), DOT2(W1, H2(wd[1]), DOT2(W2, H2(wd[2]), acc[0])));
                acc[1] = DOT2(W0, H2(wd[3]), DOT2(W1, H2(wd[4]), DOT2(W2, H2(wd[5]), acc[1])));
                acc[2] = DOT2(W1, H2(wd[0]), DOT2(W2, H2(wd[1]), DOT2(W3, H2(wd[2]), acc[2])));
                acc[3] = DOT2(W1, H2(wd[3]), DOT2(W2, H2(wd[4]), DOT2(W3, H2(wd[5]), acc[3])));
            }
        }
    }

    int oy = ty0 + ty;
    int ox = tx0 + 4 * tx;
    float4 r = {acc[0], acc[1], acc[2], acc[3]};
    *(float4*)(out + (size_t)n * 65536 + (size_t)oy * 256 + ox) = r;
}

// ---------------------------------------------------------------------------
extern "C" void kernel_launch(void* const* d_in, const int* in_sizes, int n_in,
                              void* d_out, int out_size, void* d_ws, size_t ws_size,
                              hipStream_t stream) {
    const float* x  = (const float*)d_in[0];
    const float* w1 = (const float*)d_in[1];
    const float* g1 = (const float*)d_in[2];
    const float* b1 = (const float*)d_in[3];
    const float* w2 = (const float*)d_in[4];
    const float* g2 = (const float*)d_in[5];
    const float* b2 = (const float*)d_in[6];
    const float* w3 = (const float*)d_in[7];
    float* out = (float*)d_out;

    WS ws = carve(d_ws);

    k_pack_x<<<1024, 256, 0, stream>>>(x, ws.xbits);
    k_pack_w<<<1, 256, 0, stream>>>(w1, w2, ws.wb1, ws.w2lo, ws.w2hi, ws.w2pk,
                                    ws.st1, ws.st2);
    k_stats1<<<2048, 256, 0, stream>>>(ws.xbits, ws.wb1, ws.st1);
    k_fin1<<<1, 128, 0, stream>>>(ws.st1, g1, b1, ws.wb1, ws.pk1, ws.flipm);
    k_conv2<<<4096, 256, 0, stream>>>(ws.xbits, ws.pk1, ws.flipm, ws.w2pk, ws.h2s);
    k_stats2<<<1024, 256, 0, stream>>>(ws.h2s, ws.st2);
    k_fin2<<<1, 64, 0, stream>>>(ws.st2, g2, b2, w3, ws.a2, ws.c2, ws.wtab);
    k_conv3<<<512, 512, 0, stream>>>(ws.h2s, ws.a2, ws.c2, ws.wtab, out);
}